// Round 1
// baseline (1732.019 us; speedup 1.0000x reference)
//
#include <hip/hip_runtime.h>

#define F 576
#define OUTC 256
#define SNUM 64
#define PP 576.0f

// ---------------- prep: elp[i] = exp(log_prec_lr * lp[i]) ----------------
__global__ void k_prep(const float* __restrict__ lp, float* __restrict__ elp) {
  int i = blockIdx.x * 256 + threadIdx.x;
  if (i < F) elp[i] = expf(lp[i]);   // LOG_PREC_LR == 1.0
}

// ---------------- G = (elp ⊙ X)^T X + PP*I  (lower tiles only) ----------------
__global__ __launch_bounds__(256) void k_gemm_G(const float* __restrict__ X,
                                                const float* __restrict__ elp,
                                                float* __restrict__ G) {
  int bi = blockIdx.y, bj = blockIdx.x;
  if (bj > bi) return;
  __shared__ float As[32][68];
  __shared__ float Bs[32][68];
  int t = threadIdx.x;
  int tx = t & 15, ty = t >> 4;
  int f0 = bi * 64, g0 = bj * 64;
  float acc[4][4] = {};
  for (int i0 = 0; i0 < F; i0 += 32) {
    int col = t & 63, kr = t >> 6;
#pragma unroll
    for (int kk = 0; kk < 32; kk += 4) {
      int i = i0 + kr + kk;
      float e = elp[i];
      As[kr + kk][col] = e * X[i * F + f0 + col];
      Bs[kr + kk][col] = X[i * F + g0 + col];
    }
    __syncthreads();
#pragma unroll
    for (int k = 0; k < 32; ++k) {
      float4 a4 = *(const float4*)&As[k][ty * 4];
      float4 b4 = *(const float4*)&Bs[k][tx * 4];
      float av[4] = {a4.x, a4.y, a4.z, a4.w};
      float bv[4] = {b4.x, b4.y, b4.z, b4.w};
#pragma unroll
      for (int r = 0; r < 4; ++r)
#pragma unroll
        for (int c = 0; c < 4; ++c) acc[r][c] += av[r] * bv[c];
    }
    __syncthreads();
  }
#pragma unroll
  for (int r = 0; r < 4; ++r) {
    int gr = f0 + ty * 4 + r;
#pragma unroll
    for (int c = 0; c < 4; ++c) {
      int gc = g0 + tx * 4 + c;
      float v = acc[r][c];
      if (gr == gc) v += PP;
      G[gr * F + gc] = v;
    }
  }
}

// ---------------- Y[f][o] = sum_i elp[i] X[i,f] u[o,i] ----------------
__global__ __launch_bounds__(256) void k_gemm_Y(const float* __restrict__ X,
                                                const float* __restrict__ u,
                                                const float* __restrict__ elp,
                                                float* __restrict__ Y) {
  int bo = blockIdx.x, bf = blockIdx.y;
  __shared__ float As[32][68];
  __shared__ float Bs[32][68];
  int t = threadIdx.x, tx = t & 15, ty = t >> 4;
  int f0 = bf * 64, o0 = bo * 64;
  float acc[4][4] = {};
  for (int i0 = 0; i0 < F; i0 += 32) {
    {
      int col = t & 63, kr = t >> 6;
#pragma unroll
      for (int kk = 0; kk < 32; kk += 4) {
        int i = i0 + kr + kk;
        As[kr + kk][col] = elp[i] * X[i * F + f0 + col];
      }
      int oo = t >> 2, kq = t & 3;
      const float* ur = &u[(o0 + oo) * F + i0 + kq * 8];
      float4 u0 = *(const float4*)ur;
      float4 u1 = *(const float4*)(ur + 4);
      Bs[kq * 8 + 0][oo] = u0.x; Bs[kq * 8 + 1][oo] = u0.y;
      Bs[kq * 8 + 2][oo] = u0.z; Bs[kq * 8 + 3][oo] = u0.w;
      Bs[kq * 8 + 4][oo] = u1.x; Bs[kq * 8 + 5][oo] = u1.y;
      Bs[kq * 8 + 6][oo] = u1.z; Bs[kq * 8 + 7][oo] = u1.w;
    }
    __syncthreads();
#pragma unroll
    for (int k = 0; k < 32; ++k) {
      float4 a4 = *(const float4*)&As[k][ty * 4];
      float4 b4 = *(const float4*)&Bs[k][tx * 4];
      float av[4] = {a4.x, a4.y, a4.z, a4.w};
      float bv[4] = {b4.x, b4.y, b4.z, b4.w};
#pragma unroll
      for (int r = 0; r < 4; ++r)
#pragma unroll
        for (int c = 0; c < 4; ++c) acc[r][c] += av[r] * bv[c];
    }
    __syncthreads();
  }
#pragma unroll
  for (int r = 0; r < 4; ++r) {
    float4 st = make_float4(acc[r][0], acc[r][1], acc[r][2], acc[r][3]);
    *(float4*)&Y[(f0 + ty * 4 + r) * OUTC + o0 + tx * 4] = st;
  }
}

// ---------------- Cholesky: diag block 96x96 (1 block) ----------------
__global__ __launch_bounds__(256) void k_chol_diag(float* __restrict__ G, int k0) {
  __shared__ float D[96][97];
  __shared__ float s_dj, s_inv;
  int t = threadIdx.x;
  for (int idx = t; idx < 96 * 96; idx += 256) {
    int i = idx / 96, j = idx % 96;
    D[i][j] = G[(k0 + i) * F + k0 + j];
  }
  int tx = t & 31, ty8 = t >> 5;
  for (int j = 0; j < 96; ++j) {
    __syncthreads();                 // rank-1 of prev iter done
    if (t == 0) { float d = sqrtf(D[j][j]); s_dj = d; s_inv = 1.0f / d; }
    __syncthreads();
    if (t > j && t < 96) D[t][j] *= s_inv;
    if (t == j) D[j][j] = s_dj;
    __syncthreads();
    for (int i = j + 1 + ty8; i < 96; i += 8) {
      float lij = D[i][j];
      for (int g = j + 1 + tx; g < 96; g += 32) D[i][g] -= lij * D[g][j];
    }
  }
  __syncthreads();
  for (int idx = t; idx < 96 * 96; idx += 256) {
    int i = idx / 96, j = idx % 96;
    if (j <= i) G[(k0 + i) * F + k0 + j] = D[i][j];
  }
}

// ---------------- Cholesky: panel solve (one wave per row) ----------------
__global__ __launch_bounds__(256) void k_chol_panel(float* __restrict__ G, int k0) {
  __shared__ float Ls[96][97];
  __shared__ float invd[96];
  int t = threadIdx.x;
  for (int idx = t; idx < 96 * 96; idx += 256) {
    int i = idx / 96, j = idx % 96;
    Ls[i][j] = G[(k0 + i) * F + k0 + j];
  }
  __syncthreads();
  if (t < 96) invd[t] = 1.0f / Ls[t][t];
  __syncthreads();
  int lane = t & 63, wv = t >> 6;
  int r = k0 + 96 + blockIdx.x * 4 + wv;
  float v0 = G[r * F + k0 + lane];
  float v1 = (lane < 32) ? G[r * F + k0 + 64 + lane] : 0.0f;
  for (int j = 0; j < 96; ++j) {
    float vj = (j < 64) ? __shfl(v0, j, 64) : __shfl(v1, j - 64, 64);
    vj *= invd[j];
    if (j < 64) { if (lane == j) v0 = vj; }
    else        { if (lane == j - 64) v1 = vj; }
    if (lane > j) v0 -= vj * Ls[lane][j];
    if (lane < 32) { int m = 64 + lane; if (m > j) v1 -= vj * Ls[m][j]; }
  }
  G[r * F + k0 + lane] = v0;
  if (lane < 32) G[r * F + k0 + 64 + lane] = v1;
}

// ---------------- Cholesky: trailing update  C -= P P^T (96x96 tiles) ----------------
__global__ __launch_bounds__(256) void k_chol_update(float* __restrict__ G, int k0) {
  int ti = blockIdx.y, tj = blockIdx.x;
  if (tj > ti) return;
  int b0 = k0 + 96;
  int i0 = b0 + ti * 96, j0 = b0 + tj * 96;
  __shared__ float As[32][97];
  __shared__ float Bs[32][97];
  float acc[6][6] = {};
  int t = threadIdx.x, tx = t & 15, ty = t >> 4;
  for (int kk0 = 0; kk0 < 96; kk0 += 32) {
    for (int idx = t; idx < 96 * 32; idx += 256) {
      int ii = idx >> 5, kk = idx & 31;
      As[kk][ii] = G[(i0 + ii) * F + k0 + kk0 + kk];
      Bs[kk][ii] = G[(j0 + ii) * F + k0 + kk0 + kk];
    }
    __syncthreads();
#pragma unroll
    for (int k = 0; k < 32; ++k) {
      float a[6], b[6];
#pragma unroll
      for (int m = 0; m < 6; ++m) { a[m] = As[k][ty * 6 + m]; b[m] = Bs[k][tx * 6 + m]; }
#pragma unroll
      for (int r = 0; r < 6; ++r)
#pragma unroll
        for (int c = 0; c < 6; ++c) acc[r][c] += a[r] * b[c];
    }
    __syncthreads();
  }
#pragma unroll
  for (int r = 0; r < 6; ++r)
#pragma unroll
    for (int c = 0; c < 6; ++c)
      G[(i0 + ty * 6 + r) * F + j0 + tx * 6 + c] -= acc[r][c];
}

// ---------------- LinvT[j][i] = (L^{-1})[i][j]  (one wave per column j) ----------------
__global__ __launch_bounds__(256) void k_linv(const float* __restrict__ G,
                                              float* __restrict__ LinvT) {
  int lane = threadIdx.x & 63;
  int wv = threadIdx.x >> 6;
  int j = blockIdx.x * 4 + wv;
  int qj = j >> 6;
  float w[9] = {0,0,0,0,0,0,0,0,0};
#pragma unroll
  for (int qi = 0; qi < 9; ++qi) {
    if (qi < qj) continue;
    int iistart = (qi == qj) ? (j & 63) : 0;
    for (int ii = iistart; ii < 64; ++ii) {
      int i = qi * 64 + ii;
      float sum = 0.0f;
#pragma unroll
      for (int q = 0; q < 9; ++q) {
        if (q > qi) break;
        if (q >= qj) {
          int k = q * 64 + lane;
          float lv = G[i * F + k];
          float term = lv * w[q];
          if (q == qi) term = (k < i) ? term : 0.0f;
          sum += term;
        }
      }
#pragma unroll
      for (int off = 32; off > 0; off >>= 1) sum += __shfl_xor(sum, off, 64);
      float diag = G[i * F + i];
      float val = (((i == j) ? 1.0f : 0.0f) - sum) / diag;
      if (lane == ii) w[qi] = val;
    }
  }
#pragma unroll
  for (int q = 0; q < 9; ++q) LinvT[j * F + q * 64 + lane] = w[q];
}

// ---------------- T = Linv * Y   (T[g][o]) ----------------
__global__ __launch_bounds__(256) void k_gemm_T(const float* __restrict__ LinvT,
                                                const float* __restrict__ Y,
                                                float* __restrict__ T) {
  int bo = blockIdx.x, bg = blockIdx.y;
  __shared__ float As[32][68];
  __shared__ float Bs[32][68];
  int t = threadIdx.x, tx = t & 15, ty = t >> 4;
  int g0 = bg * 64, o0 = bo * 64;
  float acc[4][4] = {};
  int kend = g0 + 64;
  for (int h0 = 0; h0 < kend; h0 += 32) {
    int col = t & 63, kr = t >> 6;
#pragma unroll
    for (int kk = 0; kk < 32; kk += 4) {
      As[kr + kk][col] = LinvT[(h0 + kr + kk) * F + g0 + col];
      Bs[kr + kk][col] = Y[(h0 + kr + kk) * OUTC + o0 + col];
    }
    __syncthreads();
#pragma unroll
    for (int k = 0; k < 32; ++k) {
      float4 a4 = *(const float4*)&As[k][ty * 4];
      float4 b4 = *(const float4*)&Bs[k][tx * 4];
      float av[4] = {a4.x, a4.y, a4.z, a4.w};
      float bv[4] = {b4.x, b4.y, b4.z, b4.w};
#pragma unroll
      for (int r = 0; r < 4; ++r)
#pragma unroll
        for (int c = 0; c < 4; ++c) acc[r][c] += av[r] * bv[c];
    }
    __syncthreads();
  }
#pragma unroll
  for (int r = 0; r < 4; ++r) {
    float4 st = make_float4(acc[r][0], acc[r][1], acc[r][2], acc[r][3]);
    *(float4*)&T[(g0 + ty * 4 + r) * OUTC + o0 + tx * 4] = st;
  }
}

// ---------------- meanT[o][f] = sum_g LinvT[f][g] T[g][o] ----------------
__global__ __launch_bounds__(256) void k_gemm_mean(const float* __restrict__ LinvT,
                                                   const float* __restrict__ T,
                                                   float* __restrict__ meanT) {
  int bf = blockIdx.x, bo = blockIdx.y;
  __shared__ float As[32][68];
  __shared__ float Bs[32][68];
  int t = threadIdx.x, tx = t & 15, ty = t >> 4;
  int f0 = bf * 64, o0 = bo * 64;
  float acc[4][4] = {};
  for (int g0 = f0; g0 < F; g0 += 32) {
    {
      int col = t & 63, kr = t >> 6;
#pragma unroll
      for (int kk = 0; kk < 32; kk += 4)
        As[kr + kk][col] = T[(g0 + kr + kk) * OUTC + o0 + col];
      int ff = t >> 2, kq = t & 3;
      const float* lr = &LinvT[(f0 + ff) * F + g0 + kq * 8];
      float4 b0 = *(const float4*)lr;
      float4 b1 = *(const float4*)(lr + 4);
      Bs[kq * 8 + 0][ff] = b0.x; Bs[kq * 8 + 1][ff] = b0.y;
      Bs[kq * 8 + 2][ff] = b0.z; Bs[kq * 8 + 3][ff] = b0.w;
      Bs[kq * 8 + 4][ff] = b1.x; Bs[kq * 8 + 5][ff] = b1.y;
      Bs[kq * 8 + 6][ff] = b1.z; Bs[kq * 8 + 7][ff] = b1.w;
    }
    __syncthreads();
#pragma unroll
    for (int k = 0; k < 32; ++k) {
      float4 a4 = *(const float4*)&As[k][ty * 4];
      float4 b4 = *(const float4*)&Bs[k][tx * 4];
      float av[4] = {a4.x, a4.y, a4.z, a4.w};
      float bv[4] = {b4.x, b4.y, b4.z, b4.w};
#pragma unroll
      for (int r = 0; r < 4; ++r)
#pragma unroll
        for (int c = 0; c < 4; ++c) acc[r][c] += av[r] * bv[c];
    }
    __syncthreads();
  }
#pragma unroll
  for (int r = 0; r < 4; ++r) {
    float4 st = make_float4(acc[r][0], acc[r][1], acc[r][2], acc[r][3]);
    *(float4*)&meanT[(o0 + ty * 4 + r) * F + f0 + tx * 4] = st;
  }
}

// ---------------- big GEMM: out[r][f] = sum_g Z[r][g] Linv[g][f] + meanT[r&255][f] ----------------
__global__ __launch_bounds__(256) void k_big(const float* __restrict__ Z,
                                             const float* __restrict__ LinvT,
                                             const float* __restrict__ meanT,
                                             float* __restrict__ out) {
  int bf = blockIdx.x, br = blockIdx.y;
  __shared__ float As[32][68];
  __shared__ float Bs[32][68];
  int t = threadIdx.x, tx = t & 15, ty = t >> 4;
  int f0 = bf * 64, r0 = br * 64;
  float acc[4][4] = {};
  for (int g0 = f0; g0 < F; g0 += 32) {
    {
      int rr = t >> 2, kq = t & 3;
      const float* zr = &Z[(r0 + rr) * F + g0 + kq * 8];
      float4 a0 = *(const float4*)zr;
      float4 a1 = *(const float4*)(zr + 4);
      As[kq * 8 + 0][rr] = a0.x; As[kq * 8 + 1][rr] = a0.y;
      As[kq * 8 + 2][rr] = a0.z; As[kq * 8 + 3][rr] = a0.w;
      As[kq * 8 + 4][rr] = a1.x; As[kq * 8 + 5][rr] = a1.y;
      As[kq * 8 + 6][rr] = a1.z; As[kq * 8 + 7][rr] = a1.w;
      const float* lr = &LinvT[(f0 + rr) * F + g0 + kq * 8];
      float4 b0 = *(const float4*)lr;
      float4 b1 = *(const float4*)(lr + 4);
      Bs[kq * 8 + 0][rr] = b0.x; Bs[kq * 8 + 1][rr] = b0.y;
      Bs[kq * 8 + 2][rr] = b0.z; Bs[kq * 8 + 3][rr] = b0.w;
      Bs[kq * 8 + 4][rr] = b1.x; Bs[kq * 8 + 5][rr] = b1.y;
      Bs[kq * 8 + 6][rr] = b1.z; Bs[kq * 8 + 7][rr] = b1.w;
    }
    __syncthreads();
#pragma unroll
    for (int k = 0; k < 32; ++k) {
      float4 a4 = *(const float4*)&As[k][ty * 4];
      float4 b4 = *(const float4*)&Bs[k][tx * 4];
      float av[4] = {a4.x, a4.y, a4.z, a4.w};
      float bv[4] = {b4.x, b4.y, b4.z, b4.w};
#pragma unroll
      for (int r = 0; r < 4; ++r)
#pragma unroll
        for (int c = 0; c < 4; ++c) acc[r][c] += av[r] * bv[c];
    }
    __syncthreads();
  }
#pragma unroll
  for (int r = 0; r < 4; ++r) {
    int row = r0 + ty * 4 + r;
    int o = row & 255;
    float4 mv = *(const float4*)&meanT[o * F + f0 + tx * 4];
    float4 st = make_float4(acc[r][0] + mv.x, acc[r][1] + mv.y,
                            acc[r][2] + mv.z, acc[r][3] + mv.w);
    *(float4*)&out[row * F + f0 + tx * 4] = st;
  }
}

// ---------------- logpq: per-(s,slice) f64 partial sums ----------------
__global__ __launch_bounds__(256) void k_logpq_part(const float* __restrict__ C,
                                                    const float* __restrict__ Zp,
                                                    double* __restrict__ parts) {
  int s = blockIdx.y, slice = blockIdx.x;
  const int per = (OUTC * F) / 8;   // 18432
  int base = s * OUTC * F + slice * per;
  double ssq = 0.0, zsq = 0.0;
  for (int idx = threadIdx.x * 4; idx < per; idx += 1024) {
    float4 c = *(const float4*)&C[base + idx];
    float4 z = *(const float4*)&Zp[base + idx];
    ssq += (double)c.x * c.x + (double)c.y * c.y + (double)c.z * c.z + (double)c.w * c.w;
    zsq += (double)z.x * z.x + (double)z.y * z.y + (double)z.z * z.z + (double)z.w * z.w;
  }
  __shared__ double sA[256], sB[256];
  sA[threadIdx.x] = ssq; sB[threadIdx.x] = zsq;
  __syncthreads();
  for (int o = 128; o > 0; o >>= 1) {
    if (threadIdx.x < o) { sA[threadIdx.x] += sA[threadIdx.x + o]; sB[threadIdx.x] += sB[threadIdx.x + o]; }
    __syncthreads();
  }
  if (threadIdx.x == 0) {
    parts[(s * 8 + slice) * 2 + 0] = sA[0];
    parts[(s * 8 + slice) * 2 + 1] = sB[0];
  }
}

// ---------------- logpq final: logdet + combine ----------------
__global__ __launch_bounds__(576) void k_logpq_final(const float* __restrict__ G,
                                                     const double* __restrict__ parts,
                                                     float* __restrict__ out) {
  __shared__ double red[576];
  int t = threadIdx.x;
  red[t] = log((double)G[t * F + t]);
  __syncthreads();
  for (int o = 512; o > 0; o >>= 1) {
    if (t < o && t + o < 576) red[t] += red[t + o];
    __syncthreads();
  }
  double ldsum = red[0];   // sum_f log(L_ff)
  if (t < SNUM) {
    double ssq = 0.0, zsq = 0.0;
    for (int k = 0; k < 8; ++k) {
      ssq += parts[(t * 8 + k) * 2 + 0];
      zsq += parts[(t * 8 + k) * 2 + 1];
    }
    double pp = 576.0;
    double lpq = -0.5 * pp * ssq
               + 0.5 * (double)(OUTC * F) * log(pp)
               + 0.5 * zsq
               - (double)OUTC * ldsum;
    out[SNUM * OUTC * F + t] = (float)lpq;
  }
}

// ---------------- launch ----------------
extern "C" void kernel_launch(void* const* d_in, const int* in_sizes, int n_in,
                              void* d_out, int out_size, void* d_ws, size_t ws_size,
                              hipStream_t stream) {
  (void)in_sizes; (void)n_in; (void)out_size; (void)ws_size;
  const float* X  = (const float*)d_in[1];   // Xi_param [1,576,576]
  const float* u  = (const float*)d_in[2];   // u [256,576,1]
  const float* lp = (const float*)d_in[3];   // log_prec_scaled [1,1,576]
  const float* Z  = (const float*)d_in[4];   // Z [64,256,576,1]
  float* out = (float*)d_out;

  float* ws    = (float*)d_ws;
  float* G     = ws;                 // 576*576
  float* LinvT = G + F * F;          // 576*576
  float* Yb    = LinvT + F * F;      // 576*256
  float* Tb    = Yb + F * OUTC;      // 576*256
  float* meanT = Tb + F * OUTC;      // 256*576
  float* elp   = meanT + F * OUTC;   // 576
  double* parts = (double*)(elp + F);  // 64*8*2 doubles (8B aligned)

  k_prep<<<3, 256, 0, stream>>>(lp, elp);
  k_gemm_G<<<dim3(9, 9), 256, 0, stream>>>(X, elp, G);
  k_gemm_Y<<<dim3(4, 9), 256, 0, stream>>>(X, u, elp, Yb);

  for (int k = 0; k < 6; ++k) {
    int k0 = k * 96;
    k_chol_diag<<<1, 256, 0, stream>>>(G, k0);
    int n = F - k0 - 96;
    if (n > 0) {
      k_chol_panel<<<n / 4, 256, 0, stream>>>(G, k0);
      k_chol_update<<<dim3(n / 96, n / 96), 256, 0, stream>>>(G, k0);
    }
  }

  k_linv<<<144, 256, 0, stream>>>(G, LinvT);
  k_gemm_T<<<dim3(4, 9), 256, 0, stream>>>(LinvT, Yb, Tb);
  k_gemm_mean<<<dim3(9, 4), 256, 0, stream>>>(LinvT, Tb, meanT);
  k_big<<<dim3(9, 256), 256, 0, stream>>>(Z, LinvT, meanT, out);
  k_logpq_part<<<dim3(8, 64), 256, 0, stream>>>(out, Z, parts);
  k_logpq_final<<<1, 576, 0, stream>>>(G, parts, out);
}

// Round 2
// 1503.309 us; speedup vs baseline: 1.1521x; 1.1521x over previous
//
#include <hip/hip_runtime.h>

#define F 576
#define OUTC 256
#define SNUM 64
#define PP 576.0f

// ---------------- G = (exp(lp) ⊙ X)^T X + PP*I  (lower tiles only) ----------------
__global__ __launch_bounds__(256) void k_gemm_G(const float* __restrict__ X,
                                                const float* __restrict__ lp,
                                                float* __restrict__ G) {
  int bi = blockIdx.y, bj = blockIdx.x;
  if (bj > bi) return;
  __shared__ float As[32][68];
  __shared__ float Bs[32][68];
  int t = threadIdx.x;
  int tx = t & 15, ty = t >> 4;
  int f0 = bi * 64, g0 = bj * 64;
  float acc[4][4] = {};
  for (int i0 = 0; i0 < F; i0 += 32) {
    int col = t & 63, kr = t >> 6;
#pragma unroll
    for (int kk = 0; kk < 32; kk += 4) {
      int i = i0 + kr + kk;
      float e = expf(lp[i]);
      As[kr + kk][col] = e * X[i * F + f0 + col];
      Bs[kr + kk][col] = X[i * F + g0 + col];
    }
    __syncthreads();
#pragma unroll
    for (int k = 0; k < 32; ++k) {
      float4 a4 = *(const float4*)&As[k][ty * 4];
      float4 b4 = *(const float4*)&Bs[k][tx * 4];
      float av[4] = {a4.x, a4.y, a4.z, a4.w};
      float bv[4] = {b4.x, b4.y, b4.z, b4.w};
#pragma unroll
      for (int r = 0; r < 4; ++r)
#pragma unroll
        for (int c = 0; c < 4; ++c) acc[r][c] += av[r] * bv[c];
    }
    __syncthreads();
  }
#pragma unroll
  for (int r = 0; r < 4; ++r) {
    int gr = f0 + ty * 4 + r;
#pragma unroll
    for (int c = 0; c < 4; ++c) {
      int gc = g0 + tx * 4 + c;
      float v = acc[r][c];
      if (gr == gc) v += PP;
      G[gr * F + gc] = v;
    }
  }
}

// ---------------- Y[f][o] = sum_i exp(lp[i]) X[i,f] u[o,i] ----------------
__global__ __launch_bounds__(256) void k_gemm_Y(const float* __restrict__ X,
                                                const float* __restrict__ u,
                                                const float* __restrict__ lp,
                                                float* __restrict__ Y) {
  int bo = blockIdx.x, bf = blockIdx.y;
  __shared__ float As[32][68];
  __shared__ float Bs[32][68];
  int t = threadIdx.x, tx = t & 15, ty = t >> 4;
  int f0 = bf * 64, o0 = bo * 64;
  float acc[4][4] = {};
  for (int i0 = 0; i0 < F; i0 += 32) {
    {
      int col = t & 63, kr = t >> 6;
#pragma unroll
      for (int kk = 0; kk < 32; kk += 4) {
        int i = i0 + kr + kk;
        As[kr + kk][col] = expf(lp[i]) * X[i * F + f0 + col];
      }
      int oo = t >> 2, kq = t & 3;
      const float* ur = &u[(o0 + oo) * F + i0 + kq * 8];
      float4 u0 = *(const float4*)ur;
      float4 u1 = *(const float4*)(ur + 4);
      Bs[kq * 8 + 0][oo] = u0.x; Bs[kq * 8 + 1][oo] = u0.y;
      Bs[kq * 8 + 2][oo] = u0.z; Bs[kq * 8 + 3][oo] = u0.w;
      Bs[kq * 8 + 4][oo] = u1.x; Bs[kq * 8 + 5][oo] = u1.y;
      Bs[kq * 8 + 6][oo] = u1.z; Bs[kq * 8 + 7][oo] = u1.w;
    }
    __syncthreads();
#pragma unroll
    for (int k = 0; k < 32; ++k) {
      float4 a4 = *(const float4*)&As[k][ty * 4];
      float4 b4 = *(const float4*)&Bs[k][tx * 4];
      float av[4] = {a4.x, a4.y, a4.z, a4.w};
      float bv[4] = {b4.x, b4.y, b4.z, b4.w};
#pragma unroll
      for (int r = 0; r < 4; ++r)
#pragma unroll
        for (int c = 0; c < 4; ++c) acc[r][c] += av[r] * bv[c];
    }
    __syncthreads();
  }
#pragma unroll
  for (int r = 0; r < 4; ++r) {
    float4 st = make_float4(acc[r][0], acc[r][1], acc[r][2], acc[r][3]);
    *(float4*)&Y[(f0 + ty * 4 + r) * OUTC + o0 + tx * 4] = st;
  }
}

// ---------------- Cholesky: diag block 96x96 (1 block, 2 syncs/col) ----------------
__global__ __launch_bounds__(256) void k_chol_diag(float* __restrict__ G, int k0) {
  __shared__ float D[96][97];
  __shared__ float diag_s[96];
  int t = threadIdx.x;
  for (int idx = t; idx < 96 * 96; idx += 256) {
    int i = idx / 96, j = idx % 96;
    D[i][j] = G[(k0 + i) * F + k0 + j];
  }
  int tx = t & 31, ty8 = t >> 5;
  for (int j = 0; j < 96; ++j) {
    __syncthreads();                 // rank-1 of prev iter (or load) done
    float dj = D[j][j];
    float inv = 1.0f / sqrtf(dj);
    if (t > j && t < 96) D[t][j] *= inv;
    if (t == j) diag_s[j] = dj * inv;
    __syncthreads();
    for (int i = j + 1 + ty8; i < 96; i += 8) {
      float lij = D[i][j];
      for (int g = j + 1 + tx; g < 96; g += 32) D[i][g] -= lij * D[g][j];
    }
  }
  __syncthreads();
  for (int idx = t; idx < 96 * 96; idx += 256) {
    int i = idx / 96, j = idx % 96;
    if (j <= i) G[(k0 + i) * F + k0 + j] = (i == j) ? diag_s[i] : D[i][j];
  }
}

// ---------------- Cholesky: panel solve (one wave per row) ----------------
__global__ __launch_bounds__(256) void k_chol_panel(float* __restrict__ G, int k0) {
  __shared__ float Ls[96][97];
  __shared__ float invd[96];
  int t = threadIdx.x;
  for (int idx = t; idx < 96 * 96; idx += 256) {
    int i = idx / 96, j = idx % 96;
    Ls[i][j] = G[(k0 + i) * F + k0 + j];
  }
  __syncthreads();
  if (t < 96) invd[t] = 1.0f / Ls[t][t];
  __syncthreads();
  int lane = t & 63, wv = t >> 6;
  int r = k0 + 96 + blockIdx.x * 4 + wv;
  float v0 = G[r * F + k0 + lane];
  float v1 = (lane < 32) ? G[r * F + k0 + 64 + lane] : 0.0f;
  for (int j = 0; j < 96; ++j) {
    float vj = (j < 64) ? __shfl(v0, j, 64) : __shfl(v1, j - 64, 64);
    vj *= invd[j];
    if (j < 64) { if (lane == j) v0 = vj; }
    else        { if (lane == j - 64) v1 = vj; }
    if (lane > j) v0 -= vj * Ls[lane][j];
    if (lane < 32) { int m = 64 + lane; if (m > j) v1 -= vj * Ls[m][j]; }
  }
  G[r * F + k0 + lane] = v0;
  if (lane < 32) G[r * F + k0 + 64 + lane] = v1;
}

// ---------------- Cholesky: trailing update  C -= P P^T (96x96 tiles) ----------------
__global__ __launch_bounds__(256) void k_chol_update(float* __restrict__ G, int k0) {
  int ti = blockIdx.y, tj = blockIdx.x;
  if (tj > ti) return;
  int b0 = k0 + 96;
  int i0 = b0 + ti * 96, j0 = b0 + tj * 96;
  __shared__ float As[32][97];
  __shared__ float Bs[32][97];
  float acc[6][6] = {};
  int t = threadIdx.x, tx = t & 15, ty = t >> 4;
  for (int kk0 = 0; kk0 < 96; kk0 += 32) {
    for (int idx = t; idx < 96 * 32; idx += 256) {
      int ii = idx >> 5, kk = idx & 31;
      As[kk][ii] = G[(i0 + ii) * F + k0 + kk0 + kk];
      Bs[kk][ii] = G[(j0 + ii) * F + k0 + kk0 + kk];
    }
    __syncthreads();
#pragma unroll
    for (int k = 0; k < 32; ++k) {
      float a[6], b[6];
#pragma unroll
      for (int m = 0; m < 6; ++m) { a[m] = As[k][ty * 6 + m]; b[m] = Bs[k][tx * 6 + m]; }
#pragma unroll
      for (int r = 0; r < 6; ++r)
#pragma unroll
        for (int c = 0; c < 6; ++c) acc[r][c] += a[r] * b[c];
    }
    __syncthreads();
  }
#pragma unroll
  for (int r = 0; r < 6; ++r)
#pragma unroll
    for (int c = 0; c < 6; ++c)
      G[(i0 + ty * 6 + r) * F + j0 + tx * 6 + c] -= acc[r][c];
}

// ---------------- zero LI ----------------
__global__ __launch_bounds__(256) void k_zero(float* __restrict__ p) {
  int idx = blockIdx.x * 256 + threadIdx.x;
  *(float4*)&p[idx * 4] = make_float4(0.f, 0.f, 0.f, 0.f);
}

// ---------------- base: invert 8 diagonal 72x72 triangular blocks of L ----------------
__global__ __launch_bounds__(256) void k_base_inv(const float* __restrict__ G,
                                                  float* __restrict__ LI) {
  __shared__ float Ls[72][73];
  __shared__ float Xs[72][73];
  __shared__ float invd[72];
  int b = blockIdx.x;
  int t = threadIdx.x;
  const float* Gb = &G[(b * 72) * F + b * 72];
  for (int idx = t; idx < 72 * 72; idx += 256) {
    int i = idx / 72, j = idx % 72;
    Ls[i][j] = Gb[i * F + j];
    Xs[i][j] = (i == j) ? 1.0f : 0.0f;
  }
  __syncthreads();
  if (t < 72) invd[t] = 1.0f / Ls[t][t];
  __syncthreads();
  for (int r = 0; r < 72; ++r) {
    if (t < 72) Xs[r][t] *= invd[r];
    __syncthreads();
    int rem = (71 - r) * 72;
    for (int idx = t; idx < rem; idx += 256) {
      int i = r + 1 + idx / 72, c = idx % 72;
      Xs[i][c] -= Ls[i][r] * Xs[r][c];
    }
    __syncthreads();
  }
  float* Ob = &LI[(b * 72) * F + b * 72];
  for (int idx = t; idx < 72 * 72; idx += 256) {
    int i = idx / 72, j = idx % 72;
    Ob[i * F + j] = Xs[i][j];
  }
}

// ---------------- generic masked tiled GEMM: C = sgn * A@B (batched over z) ----------------
__global__ __launch_bounds__(256) void k_trigemm(const float* __restrict__ A, int lda, int aZ,
                                                 const float* __restrict__ B, int ldb, int bZ,
                                                 float* __restrict__ C, int ldc, int cZ,
                                                 int M, int N, int K, float sgn) {
  int z = blockIdx.z;
  A += (size_t)z * aZ; B += (size_t)z * bZ; C += (size_t)z * cZ;
  int m0 = blockIdx.y * 64, n0 = blockIdx.x * 64;
  __shared__ float As[32][68];
  __shared__ float Bs[32][68];
  int t = threadIdx.x, tx = t & 15, ty = t >> 4;
  float acc[4][4] = {};
  for (int k0 = 0; k0 < K; k0 += 32) {
    {
      int rr = t >> 2, kq = t & 3;
      int row = m0 + rr;
#pragma unroll
      for (int e = 0; e < 8; ++e) {
        int k = kq * 8 + e;
        float v = 0.0f;
        if (row < M && k0 + k < K) v = A[row * lda + k0 + k];
        As[k][rr] = v;
      }
      int col = t & 63, kr = t >> 6;
#pragma unroll
      for (int kk = 0; kk < 32; kk += 4) {
        int k = k0 + kr + kk;
        float v = 0.0f;
        if (k < K && n0 + col < N) v = B[k * ldb + n0 + col];
        Bs[kr + kk][col] = v;
      }
    }
    __syncthreads();
#pragma unroll
    for (int k = 0; k < 32; ++k) {
      float4 a4 = *(const float4*)&As[k][ty * 4];
      float4 b4 = *(const float4*)&Bs[k][tx * 4];
      float av[4] = {a4.x, a4.y, a4.z, a4.w};
      float bv[4] = {b4.x, b4.y, b4.z, b4.w};
#pragma unroll
      for (int r = 0; r < 4; ++r)
#pragma unroll
        for (int c = 0; c < 4; ++c) acc[r][c] += av[r] * bv[c];
    }
    __syncthreads();
  }
#pragma unroll
  for (int r = 0; r < 4; ++r) {
    int row = m0 + ty * 4 + r;
    if (row >= M) continue;
#pragma unroll
    for (int c = 0; c < 4; ++c) {
      int cc = n0 + tx * 4 + c;
      if (cc < N) C[row * ldc + cc] = sgn * acc[r][c];
    }
  }
}

// ---------------- T = Linv @ Y   (T[g][o]) ----------------
__global__ __launch_bounds__(256) void k_gemm_T(const float* __restrict__ LI,
                                                const float* __restrict__ Y,
                                                float* __restrict__ T) {
  int bo = blockIdx.x, bg = blockIdx.y;
  __shared__ float As[32][68];
  __shared__ float Bs[32][68];
  int t = threadIdx.x, tx = t & 15, ty = t >> 4;
  int g0 = bg * 64, o0 = bo * 64;
  float acc[4][4] = {};
  int kend = g0 + 64;
  for (int h0 = 0; h0 < kend; h0 += 32) {
    {
      // As[k][g_local] = Linv[g0+g_local][h0+k]  (transpose-on-load, coalesced)
      int rr = t >> 2, kq = t & 3;
      const float* lp4 = &LI[(g0 + rr) * F + h0 + kq * 8];
      float4 a0 = *(const float4*)lp4;
      float4 a1 = *(const float4*)(lp4 + 4);
      As[kq * 8 + 0][rr] = a0.x; As[kq * 8 + 1][rr] = a0.y;
      As[kq * 8 + 2][rr] = a0.z; As[kq * 8 + 3][rr] = a0.w;
      As[kq * 8 + 4][rr] = a1.x; As[kq * 8 + 5][rr] = a1.y;
      As[kq * 8 + 6][rr] = a1.z; As[kq * 8 + 7][rr] = a1.w;
      int col = t & 63, kr = t >> 6;
#pragma unroll
      for (int kk = 0; kk < 32; kk += 4)
        Bs[kr + kk][col] = Y[(h0 + kr + kk) * OUTC + o0 + col];
    }
    __syncthreads();
#pragma unroll
    for (int k = 0; k < 32; ++k) {
      float4 a4 = *(const float4*)&As[k][ty * 4];
      float4 b4 = *(const float4*)&Bs[k][tx * 4];
      float av[4] = {a4.x, a4.y, a4.z, a4.w};
      float bv[4] = {b4.x, b4.y, b4.z, b4.w};
#pragma unroll
      for (int r = 0; r < 4; ++r)
#pragma unroll
        for (int c = 0; c < 4; ++c) acc[r][c] += av[r] * bv[c];
    }
    __syncthreads();
  }
#pragma unroll
  for (int r = 0; r < 4; ++r) {
    float4 st = make_float4(acc[r][0], acc[r][1], acc[r][2], acc[r][3]);
    *(float4*)&T[(g0 + ty * 4 + r) * OUTC + o0 + tx * 4] = st;
  }
}

// ---------------- meanT[o][f] = sum_g Linv[g][f] T[g][o] ----------------
__global__ __launch_bounds__(256) void k_gemm_mean(const float* __restrict__ LI,
                                                   const float* __restrict__ T,
                                                   float* __restrict__ meanT) {
  int bf = blockIdx.x, bo = blockIdx.y;
  __shared__ float As[32][68];
  __shared__ float Bs[32][68];
  int t = threadIdx.x, tx = t & 15, ty = t >> 4;
  int f0 = bf * 64, o0 = bo * 64;
  float acc[4][4] = {};
  for (int g0 = f0; g0 < F; g0 += 32) {
    {
      int col = t & 63, kr = t >> 6;
#pragma unroll
      for (int kk = 0; kk < 32; kk += 4) {
        As[kr + kk][col] = T[(g0 + kr + kk) * OUTC + o0 + col];
        Bs[kr + kk][col] = LI[(g0 + kr + kk) * F + f0 + col];
      }
    }
    __syncthreads();
#pragma unroll
    for (int k = 0; k < 32; ++k) {
      float4 a4 = *(const float4*)&As[k][ty * 4];
      float4 b4 = *(const float4*)&Bs[k][tx * 4];
      float av[4] = {a4.x, a4.y, a4.z, a4.w};
      float bv[4] = {b4.x, b4.y, b4.z, b4.w};
#pragma unroll
      for (int r = 0; r < 4; ++r)
#pragma unroll
        for (int c = 0; c < 4; ++c) acc[r][c] += av[r] * bv[c];
    }
    __syncthreads();
  }
#pragma unroll
  for (int r = 0; r < 4; ++r) {
    float4 st = make_float4(acc[r][0], acc[r][1], acc[r][2], acc[r][3]);
    *(float4*)&meanT[(o0 + ty * 4 + r) * F + f0 + tx * 4] = st;
  }
}

// ---------------- big GEMM: out[r][f] = sum_g Z[r][g] Linv[g][f] + meanT[r&255][f] ----------------
__global__ __launch_bounds__(256) void k_big(const float* __restrict__ Z,
                                             const float* __restrict__ LI,
                                             const float* __restrict__ meanT,
                                             float* __restrict__ out) {
  int bf = blockIdx.x, br = blockIdx.y;
  __shared__ float As[32][68];
  __shared__ float Bs[32][68];
  int t = threadIdx.x, tx = t & 15, ty = t >> 4;
  int f0 = bf * 64, r0 = br * 64;
  float acc[4][4] = {};
  for (int g0 = f0; g0 < F; g0 += 32) {
    {
      int rr = t >> 2, kq = t & 3;
      const float* zr = &Z[(r0 + rr) * F + g0 + kq * 8];
      float4 a0 = *(const float4*)zr;
      float4 a1 = *(const float4*)(zr + 4);
      As[kq * 8 + 0][rr] = a0.x; As[kq * 8 + 1][rr] = a0.y;
      As[kq * 8 + 2][rr] = a0.z; As[kq * 8 + 3][rr] = a0.w;
      As[kq * 8 + 4][rr] = a1.x; As[kq * 8 + 5][rr] = a1.y;
      As[kq * 8 + 6][rr] = a1.z; As[kq * 8 + 7][rr] = a1.w;
      int col = t & 63, kr = t >> 6;
#pragma unroll
      for (int kk = 0; kk < 32; kk += 4)
        Bs[kr + kk][col] = LI[(g0 + kr + kk) * F + f0 + col];
    }
    __syncthreads();
#pragma unroll
    for (int k = 0; k < 32; ++k) {
      float4 a4 = *(const float4*)&As[k][ty * 4];
      float4 b4 = *(const float4*)&Bs[k][tx * 4];
      float av[4] = {a4.x, a4.y, a4.z, a4.w};
      float bv[4] = {b4.x, b4.y, b4.z, b4.w};
#pragma unroll
      for (int r = 0; r < 4; ++r)
#pragma unroll
        for (int c = 0; c < 4; ++c) acc[r][c] += av[r] * bv[c];
    }
    __syncthreads();
  }
#pragma unroll
  for (int r = 0; r < 4; ++r) {
    int row = r0 + ty * 4 + r;
    int o = row & 255;
    float4 mv = *(const float4*)&meanT[o * F + f0 + tx * 4];
    float4 st = make_float4(acc[r][0] + mv.x, acc[r][1] + mv.y,
                            acc[r][2] + mv.z, acc[r][3] + mv.w);
    *(float4*)&out[row * F + f0 + tx * 4] = st;
  }
}

// ---------------- logpq: per-(s,slice) f64 partial sums ----------------
__global__ __launch_bounds__(256) void k_logpq_part(const float* __restrict__ C,
                                                    const float* __restrict__ Zp,
                                                    double* __restrict__ parts) {
  int s = blockIdx.y, slice = blockIdx.x;
  const int per = (OUTC * F) / 8;   // 18432
  int base = s * OUTC * F + slice * per;
  double ssq = 0.0, zsq = 0.0;
  for (int idx = threadIdx.x * 4; idx < per; idx += 1024) {
    float4 c = *(const float4*)&C[base + idx];
    float4 z = *(const float4*)&Zp[base + idx];
    ssq += (double)c.x * c.x + (double)c.y * c.y + (double)c.z * c.z + (double)c.w * c.w;
    zsq += (double)z.x * z.x + (double)z.y * z.y + (double)z.z * z.z + (double)z.w * z.w;
  }
  __shared__ double sA[256], sB[256];
  sA[threadIdx.x] = ssq; sB[threadIdx.x] = zsq;
  __syncthreads();
  for (int o = 128; o > 0; o >>= 1) {
    if (threadIdx.x < o) { sA[threadIdx.x] += sA[threadIdx.x + o]; sB[threadIdx.x] += sB[threadIdx.x + o]; }
    __syncthreads();
  }
  if (threadIdx.x == 0) {
    parts[(s * 8 + slice) * 2 + 0] = sA[0];
    parts[(s * 8 + slice) * 2 + 1] = sB[0];
  }
}

// ---------------- logpq final: logdet + combine ----------------
__global__ __launch_bounds__(576) void k_logpq_final(const float* __restrict__ G,
                                                     const double* __restrict__ parts,
                                                     float* __restrict__ out) {
  __shared__ double red[576];
  int t = threadIdx.x;
  red[t] = log((double)G[t * F + t]);
  __syncthreads();
  for (int o = 512; o > 0; o >>= 1) {
    if (t < o && t + o < 576) red[t] += red[t + o];
    __syncthreads();
  }
  double ldsum = red[0];   // sum_f log(L_ff)
  if (t < SNUM) {
    double ssq = 0.0, zsq = 0.0;
    for (int k = 0; k < 8; ++k) {
      ssq += parts[(t * 8 + k) * 2 + 0];
      zsq += parts[(t * 8 + k) * 2 + 1];
    }
    double pp = 576.0;
    double lpq = -0.5 * pp * ssq
               + 0.5 * (double)(OUTC * F) * log(pp)
               + 0.5 * zsq
               - (double)OUTC * ldsum;
    out[SNUM * OUTC * F + t] = (float)lpq;
  }
}

// ---------------- launch ----------------
extern "C" void kernel_launch(void* const* d_in, const int* in_sizes, int n_in,
                              void* d_out, int out_size, void* d_ws, size_t ws_size,
                              hipStream_t stream) {
  (void)in_sizes; (void)n_in; (void)out_size; (void)ws_size;
  const float* X  = (const float*)d_in[1];   // Xi_param [1,576,576]
  const float* u  = (const float*)d_in[2];   // u [256,576,1]
  const float* lp = (const float*)d_in[3];   // log_prec_scaled [1,1,576]
  const float* Z  = (const float*)d_in[4];   // Z [64,256,576,1]
  float* out = (float*)d_out;

  float* ws    = (float*)d_ws;
  float* G     = ws;                 // 576*576
  float* LI    = G + F * F;          // 576*576 (Linv, natural orientation)
  float* Yb    = LI + F * F;         // 576*256
  float* Tb    = Yb + F * OUTC;      // 576*256  (also aliased as trigemm temp Tw)
  float* meanT = Tb + F * OUTC;      // 256*576
  double* parts = (double*)(meanT + F * OUTC);  // 64*8*2 doubles
  float* Tw = Tb;                    // inversion temp (consumed before k_gemm_T writes Tb)

  k_gemm_G<<<dim3(9, 9), 256, 0, stream>>>(X, lp, G);
  k_gemm_Y<<<dim3(4, 9), 256, 0, stream>>>(X, u, lp, Yb);

  for (int k = 0; k < 6; ++k) {
    int k0 = k * 96;
    k_chol_diag<<<1, 256, 0, stream>>>(G, k0);
    int n = F - k0 - 96;
    if (n > 0) {
      k_chol_panel<<<n / 4, 256, 0, stream>>>(G, k0);
      k_chol_update<<<dim3(n / 96, n / 96), 256, 0, stream>>>(G, k0);
    }
  }

  // ---- recursive blocked triangular inverse: LI = inv(L) ----
  k_zero<<<(F * F) / 1024, 256, 0, stream>>>(LI);
  k_base_inv<<<8, 256, 0, stream>>>(G, LI);
  // level n=72 (4 pairs): T = B @ Ainv ; LI21 = -Cinv @ T
  k_trigemm<<<dim3(2, 2, 4), 256, 0, stream>>>(G + 72 * F, F, 144 * (F + 1),
                                               LI, F, 144 * (F + 1),
                                               Tw, 72, 72 * 72, 72, 72, 72, 1.0f);
  k_trigemm<<<dim3(2, 2, 4), 256, 0, stream>>>(LI + 72 * (F + 1), F, 144 * (F + 1),
                                               Tw, 72, 72 * 72,
                                               LI + 72 * F, F, 144 * (F + 1), 72, 72, 72, -1.0f);
  // level n=144 (2 pairs)
  k_trigemm<<<dim3(3, 3, 2), 256, 0, stream>>>(G + 144 * F, F, 288 * (F + 1),
                                               LI, F, 288 * (F + 1),
                                               Tw, 144, 144 * 144, 144, 144, 144, 1.0f);
  k_trigemm<<<dim3(3, 3, 2), 256, 0, stream>>>(LI + 144 * (F + 1), F, 288 * (F + 1),
                                               Tw, 144, 144 * 144,
                                               LI + 144 * F, F, 288 * (F + 1), 144, 144, 144, -1.0f);
  // level n=288 (1 pair)
  k_trigemm<<<dim3(5, 5, 1), 256, 0, stream>>>(G + 288 * F, F, 0,
                                               LI, F, 0,
                                               Tw, 288, 0, 288, 288, 288, 1.0f);
  k_trigemm<<<dim3(5, 5, 1), 256, 0, stream>>>(LI + 288 * (F + 1), F, 0,
                                               Tw, 288, 0,
                                               LI + 288 * F, F, 0, 288, 288, 288, -1.0f);

  k_gemm_T<<<dim3(4, 9), 256, 0, stream>>>(LI, Yb, Tb);
  k_gemm_mean<<<dim3(9, 4), 256, 0, stream>>>(LI, Tb, meanT);
  k_big<<<dim3(9, 256), 256, 0, stream>>>(Z, LI, meanT, out);
  k_logpq_part<<<dim3(8, 64), 256, 0, stream>>>(out, Z, parts);
  k_logpq_final<<<1, 576, 0, stream>>>(G, parts, out);
}

// Round 5
// 894.888 us; speedup vs baseline: 1.9355x; 1.6799x over previous
//
#include <hip/hip_runtime.h>

#define F 576
#define OUTC 256
#define SNUM 64
#define PP 576.0f

// ---------------- G = (exp(lp) ⊙ X)^T X + PP*I  (lower tiles only) ----------------
__global__ __launch_bounds__(256) void k_gemm_G(const float* __restrict__ X,
                                                const float* __restrict__ lp,
                                                float* __restrict__ G) {
  int bi = blockIdx.y, bj = blockIdx.x;
  if (bj > bi) return;
  __shared__ float As[32][68];
  __shared__ float Bs[32][68];
  int t = threadIdx.x;
  int tx = t & 15, ty = t >> 4;
  int f0 = bi * 64, g0 = bj * 64;
  float acc[4][4] = {};
  for (int i0 = 0; i0 < F; i0 += 32) {
    int col = t & 63, kr = t >> 6;
#pragma unroll
    for (int kk = 0; kk < 32; kk += 4) {
      int i = i0 + kr + kk;
      float e = expf(lp[i]);
      As[kr + kk][col] = e * X[i * F + f0 + col];
      Bs[kr + kk][col] = X[i * F + g0 + col];
    }
    __syncthreads();
#pragma unroll
    for (int k = 0; k < 32; ++k) {
      float4 a4 = *(const float4*)&As[k][ty * 4];
      float4 b4 = *(const float4*)&Bs[k][tx * 4];
      float av[4] = {a4.x, a4.y, a4.z, a4.w};
      float bv[4] = {b4.x, b4.y, b4.z, b4.w};
#pragma unroll
      for (int r = 0; r < 4; ++r)
#pragma unroll
        for (int c = 0; c < 4; ++c) acc[r][c] += av[r] * bv[c];
    }
    __syncthreads();
  }
#pragma unroll
  for (int r = 0; r < 4; ++r) {
    int gr = f0 + ty * 4 + r;
#pragma unroll
    for (int c = 0; c < 4; ++c) {
      int gc = g0 + tx * 4 + c;
      float v = acc[r][c];
      if (gr == gc) v += PP;
      G[gr * F + gc] = v;
    }
  }
}

// ---------------- Y[f][o] = sum_i exp(lp[i]) X[i,f] u[o,i] ----------------
__global__ __launch_bounds__(256) void k_gemm_Y(const float* __restrict__ X,
                                                const float* __restrict__ u,
                                                const float* __restrict__ lp,
                                                float* __restrict__ Y) {
  int bo = blockIdx.x, bf = blockIdx.y;
  __shared__ float As[32][68];
  __shared__ float Bs[32][68];
  int t = threadIdx.x, tx = t & 15, ty = t >> 4;
  int f0 = bf * 64, o0 = bo * 64;
  float acc[4][4] = {};
  for (int i0 = 0; i0 < F; i0 += 32) {
    {
      int col = t & 63, kr = t >> 6;
#pragma unroll
      for (int kk = 0; kk < 32; kk += 4) {
        int i = i0 + kr + kk;
        As[kr + kk][col] = expf(lp[i]) * X[i * F + f0 + col];
      }
      int oo = t >> 2, kq = t & 3;
      const float* ur = &u[(o0 + oo) * F + i0 + kq * 8];
      float4 u0 = *(const float4*)ur;
      float4 u1 = *(const float4*)(ur + 4);
      Bs[kq * 8 + 0][oo] = u0.x; Bs[kq * 8 + 1][oo] = u0.y;
      Bs[kq * 8 + 2][oo] = u0.z; Bs[kq * 8 + 3][oo] = u0.w;
      Bs[kq * 8 + 4][oo] = u1.x; Bs[kq * 8 + 5][oo] = u1.y;
      Bs[kq * 8 + 6][oo] = u1.z; Bs[kq * 8 + 7][oo] = u1.w;
    }
    __syncthreads();
#pragma unroll
    for (int k = 0; k < 32; ++k) {
      float4 a4 = *(const float4*)&As[k][ty * 4];
      float4 b4 = *(const float4*)&Bs[k][tx * 4];
      float av[4] = {a4.x, a4.y, a4.z, a4.w};
      float bv[4] = {b4.x, b4.y, b4.z, b4.w};
#pragma unroll
      for (int r = 0; r < 4; ++r)
#pragma unroll
        for (int c = 0; c < 4; ++c) acc[r][c] += av[r] * bv[c];
    }
    __syncthreads();
  }
#pragma unroll
  for (int r = 0; r < 4; ++r) {
    float4 st = make_float4(acc[r][0], acc[r][1], acc[r][2], acc[r][3]);
    *(float4*)&Y[(f0 + ty * 4 + r) * OUTC + o0 + tx * 4] = st;
  }
}

// ---------------- Cholesky: 64x64 diag block, one wave, register rows + __shfl ----------------
__global__ __launch_bounds__(64) void k_chol_diag64(float* __restrict__ G, int k0) {
  __shared__ float T[64][65];
  int l = threadIdx.x;
  for (int i = 0; i < 64; ++i) T[i][l] = G[(k0 + i) * F + k0 + l];
  __syncthreads();
  float r[64];
#pragma unroll
  for (int g = 0; g < 64; ++g) r[g] = T[l][g];   // lane l holds row l
#pragma unroll
  for (int j = 0; j < 64; ++j) {
    float d = __shfl(r[j], j, 64);
    float inv = 1.0f / sqrtf(d);
    float c = r[j] * inv;                        // scaled column j (valid for l >= j)
    r[j] = c;
#pragma unroll
    for (int g = j + 1; g < 64; ++g) {
      float cg = __shfl(c, g, 64);               // L[g][j]
      r[g] = fmaf(-cg, c, r[g]);
    }
  }
  __syncthreads();
#pragma unroll
  for (int g = 0; g < 64; ++g) T[l][g] = r[g];
  __syncthreads();
  for (int i = 0; i < 64; ++i)
    if (l <= i) G[(k0 + i) * F + k0 + l] = T[i][l];   // lower triangle only
}

// ---------------- Cholesky: panel solve (NB=64, 4 rows/wave) ----------------
__global__ __launch_bounds__(256) void k_chol_panel64(float* __restrict__ G, int k0) {
  __shared__ float Ls[64][65];
  __shared__ float invd[64];
  int t = threadIdx.x;
  for (int idx = t; idx < 64 * 64; idx += 256) {
    int i = idx >> 6, j = idx & 63;
    Ls[i][j] = G[(k0 + i) * F + k0 + j];
  }
  __syncthreads();
  if (t < 64) invd[t] = 1.0f / Ls[t][t];
  __syncthreads();
  int l = t & 63, w = t >> 6;
  int r0 = k0 + 64 + blockIdx.x * 16 + w * 4;
  float v0 = G[(r0 + 0) * F + k0 + l];
  float v1 = G[(r0 + 1) * F + k0 + l];
  float v2 = G[(r0 + 2) * F + k0 + l];
  float v3 = G[(r0 + 3) * F + k0 + l];
#pragma unroll
  for (int j = 0; j < 64; ++j) {
    float dj = invd[j];
    float x0 = __shfl(v0, j, 64) * dj;
    float x1 = __shfl(v1, j, 64) * dj;
    float x2 = __shfl(v2, j, 64) * dj;
    float x3 = __shfl(v3, j, 64) * dj;
    if (l > j) {
      float lj = Ls[l][j];
      v0 = fmaf(-x0, lj, v0);
      v1 = fmaf(-x1, lj, v1);
      v2 = fmaf(-x2, lj, v2);
      v3 = fmaf(-x3, lj, v3);
    }
  }
  float dl = invd[l];
  G[(r0 + 0) * F + k0 + l] = v0 * dl;
  G[(r0 + 1) * F + k0 + l] = v1 * dl;
  G[(r0 + 2) * F + k0 + l] = v2 * dl;
  G[(r0 + 3) * F + k0 + l] = v3 * dl;
}

// ---------------- Cholesky: rank-64 trailing update ----------------
__global__ __launch_bounds__(256) void k_chol_upd64(float* __restrict__ G, int k0) {
  int ti = blockIdx.y, tj = blockIdx.x;
  if (tj > ti) return;
  int b0 = k0 + 64;
  int i0 = b0 + ti * 64, j0 = b0 + tj * 64;
  __shared__ float As[32][68];
  __shared__ float Bs[32][68];
  float acc[4][4] = {};
  int t = threadIdx.x, tx = t & 15, ty = t >> 4;
  for (int kk0 = 0; kk0 < 64; kk0 += 32) {
    for (int idx = t; idx < 64 * 32; idx += 256) {
      int ii = idx >> 5, kk = idx & 31;
      As[kk][ii] = G[(i0 + ii) * F + k0 + kk0 + kk];
      Bs[kk][ii] = G[(j0 + ii) * F + k0 + kk0 + kk];
    }
    __syncthreads();
#pragma unroll
    for (int k = 0; k < 32; ++k) {
      float a[4], b[4];
#pragma unroll
      for (int m = 0; m < 4; ++m) { a[m] = As[k][ty * 4 + m]; b[m] = Bs[k][tx * 4 + m]; }
#pragma unroll
      for (int r = 0; r < 4; ++r)
#pragma unroll
        for (int c = 0; c < 4; ++c) acc[r][c] += a[r] * b[c];
    }
    __syncthreads();
  }
#pragma unroll
  for (int r = 0; r < 4; ++r)
#pragma unroll
    for (int c = 0; c < 4; ++c)
      G[(i0 + ty * 4 + r) * F + j0 + tx * 4 + c] -= acc[r][c];
}

// ---------------- zero LI ----------------
__global__ __launch_bounds__(256) void k_zero(float* __restrict__ p) {
  int idx = blockIdx.x * 256 + threadIdx.x;
  *(float4*)&p[idx * 4] = make_float4(0.f, 0.f, 0.f, 0.f);
}

// ---------------- base: invert 9 diagonal 64x64 triangular blocks (shfl, 16 cols/wave) ----------------
__global__ __launch_bounds__(256) void k_base_inv64(const float* __restrict__ G,
                                                    float* __restrict__ LI) {
  __shared__ float Ls[64][65];
  __shared__ float invd[64];
  int b = blockIdx.x, base = b * 64;
  int t = threadIdx.x;
  for (int idx = t; idx < 64 * 64; idx += 256) {
    int i = idx >> 6, j = idx & 63;
    Ls[i][j] = G[(base + i) * F + base + j];
  }
  __syncthreads();
  if (t < 64) invd[t] = 1.0f / Ls[t][t];
  __syncthreads();
  int l = t & 63, w = t >> 6;
  float v[16];
#pragma unroll
  for (int c = 0; c < 16; ++c) v[c] = (l == (w * 16 + c)) ? 1.0f : 0.0f;
#pragma unroll
  for (int j = 0; j < 64; ++j) {
    float dj = invd[j];
    float lj = (l > j) ? Ls[l][j] : 0.0f;
#pragma unroll
    for (int c = 0; c < 16; ++c) {
      float x = __shfl(v[c], j, 64) * dj;
      v[c] = fmaf(-x, lj, v[c]);
    }
  }
  float dl = invd[l];
#pragma unroll
  for (int c = 0; c < 16; ++c)
    LI[(base + l) * F + base + w * 16 + c] = v[c] * dl;
}

// ---------------- generic masked tiled GEMM: C = sgn * A@B (batched over z) ----------------
__global__ __launch_bounds__(256) void k_trigemm(const float* __restrict__ A, int lda, int aZ,
                                                 const float* __restrict__ B, int ldb, int bZ,
                                                 float* __restrict__ C, int ldc, int cZ,
                                                 int M, int N, int K, float sgn) {
  int z = blockIdx.z;
  A += (size_t)z * aZ; B += (size_t)z * bZ; C += (size_t)z * cZ;
  int m0 = blockIdx.y * 64, n0 = blockIdx.x * 64;
  __shared__ float As[32][68];
  __shared__ float Bs[32][68];
  int t = threadIdx.x, tx = t & 15, ty = t >> 4;
  float acc[4][4] = {};
  for (int k0 = 0; k0 < K; k0 += 32) {
    {
      int rr = t >> 2, kq = t & 3;
      int row = m0 + rr;
#pragma unroll
      for (int e = 0; e < 8; ++e) {
        int k = kq * 8 + e;
        float v = 0.0f;
        if (row < M && k0 + k < K) v = A[row * lda + k0 + k];
        As[k][rr] = v;
      }
      int col = t & 63, kr = t >> 6;
#pragma unroll
      for (int kk = 0; kk < 32; kk += 4) {
        int k = k0 + kr + kk;
        float v = 0.0f;
        if (k < K && n0 + col < N) v = B[k * ldb + n0 + col];
        Bs[kr + kk][col] = v;
      }
    }
    __syncthreads();
#pragma unroll
    for (int k = 0; k < 32; ++k) {
      float4 a4 = *(const float4*)&As[k][ty * 4];
      float4 b4 = *(const float4*)&Bs[k][tx * 4];
      float av[4] = {a4.x, a4.y, a4.z, a4.w};
      float bv[4] = {b4.x, b4.y, b4.z, b4.w};
#pragma unroll
      for (int r = 0; r < 4; ++r)
#pragma unroll
        for (int c = 0; c < 4; ++c) acc[r][c] += av[r] * bv[c];
    }
    __syncthreads();
  }
#pragma unroll
  for (int r = 0; r < 4; ++r) {
    int row = m0 + ty * 4 + r;
    if (row >= M) continue;
#pragma unroll
    for (int c = 0; c < 4; ++c) {
      int cc = n0 + tx * 4 + c;
      if (cc < N) C[row * ldc + cc] = sgn * acc[r][c];
    }
  }
}

// ---------------- T = Linv @ Y   (T[g][o]) ----------------
__global__ __launch_bounds__(256) void k_gemm_T(const float* __restrict__ LI,
                                                const float* __restrict__ Y,
                                                float* __restrict__ T) {
  int bo = blockIdx.x, bg = blockIdx.y;
  __shared__ float As[32][68];
  __shared__ float Bs[32][68];
  int t = threadIdx.x, tx = t & 15, ty = t >> 4;
  int g0 = bg * 64, o0 = bo * 64;
  float acc[4][4] = {};
  int kend = g0 + 64;
  for (int h0 = 0; h0 < kend; h0 += 32) {
    {
      int rr = t >> 2, kq = t & 3;
      const float* lp4 = &LI[(g0 + rr) * F + h0 + kq * 8];
      float4 a0 = *(const float4*)lp4;
      float4 a1 = *(const float4*)(lp4 + 4);
      As[kq * 8 + 0][rr] = a0.x; As[kq * 8 + 1][rr] = a0.y;
      As[kq * 8 + 2][rr] = a0.z; As[kq * 8 + 3][rr] = a0.w;
      As[kq * 8 + 4][rr] = a1.x; As[kq * 8 + 5][rr] = a1.y;
      As[kq * 8 + 6][rr] = a1.z; As[kq * 8 + 7][rr] = a1.w;
      int col = t & 63, kr = t >> 6;
#pragma unroll
      for (int kk = 0; kk < 32; kk += 4)
        Bs[kr + kk][col] = Y[(h0 + kr + kk) * OUTC + o0 + col];
    }
    __syncthreads();
#pragma unroll
    for (int k = 0; k < 32; ++k) {
      float4 a4 = *(const float4*)&As[k][ty * 4];
      float4 b4 = *(const float4*)&Bs[k][tx * 4];
      float av[4] = {a4.x, a4.y, a4.z, a4.w};
      float bv[4] = {b4.x, b4.y, b4.z, b4.w};
#pragma unroll
      for (int r = 0; r < 4; ++r)
#pragma unroll
        for (int c = 0; c < 4; ++c) acc[r][c] += av[r] * bv[c];
    }
    __syncthreads();
  }
#pragma unroll
  for (int r = 0; r < 4; ++r) {
    float4 st = make_float4(acc[r][0], acc[r][1], acc[r][2], acc[r][3]);
    *(float4*)&T[(g0 + ty * 4 + r) * OUTC + o0 + tx * 4] = st;
  }
}

// ---------------- meanT[o][f] = sum_g Linv[g][f] T[g][o] ----------------
__global__ __launch_bounds__(256) void k_gemm_mean(const float* __restrict__ LI,
                                                   const float* __restrict__ T,
                                                   float* __restrict__ meanT) {
  int bf = blockIdx.x, bo = blockIdx.y;
  __shared__ float As[32][68];
  __shared__ float Bs[32][68];
  int t = threadIdx.x, tx = t & 15, ty = t >> 4;
  int f0 = bf * 64, o0 = bo * 64;
  float acc[4][4] = {};
  for (int g0 = f0; g0 < F; g0 += 32) {
    {
      int col = t & 63, kr = t >> 6;
#pragma unroll
      for (int kk = 0; kk < 32; kk += 4) {
        As[kr + kk][col] = T[(g0 + kr + kk) * OUTC + o0 + col];
        Bs[kr + kk][col] = LI[(g0 + kr + kk) * F + f0 + col];
      }
    }
    __syncthreads();
#pragma unroll
    for (int k = 0; k < 32; ++k) {
      float4 a4 = *(const float4*)&As[k][ty * 4];
      float4 b4 = *(const float4*)&Bs[k][tx * 4];
      float av[4] = {a4.x, a4.y, a4.z, a4.w};
      float bv[4] = {b4.x, b4.y, b4.z, b4.w};
#pragma unroll
      for (int r = 0; r < 4; ++r)
#pragma unroll
        for (int c = 0; c < 4; ++c) acc[r][c] += av[r] * bv[c];
    }
    __syncthreads();
  }
#pragma unroll
  for (int r = 0; r < 4; ++r) {
    float4 st = make_float4(acc[r][0], acc[r][1], acc[r][2], acc[r][3]);
    *(float4*)&meanT[(o0 + ty * 4 + r) * F + f0 + tx * 4] = st;
  }
}

// ---------------- big GEMM: out[r][f] = sum_g Z[r][g] Linv[g][f] + meanT[r&255][f] ----------------
__global__ __launch_bounds__(256) void k_big(const float* __restrict__ Z,
                                             const float* __restrict__ LI,
                                             const float* __restrict__ meanT,
                                             float* __restrict__ out) {
  int bf = blockIdx.x, br = blockIdx.y;
  __shared__ float As[32][68];
  __shared__ float Bs[32][68];
  int t = threadIdx.x, tx = t & 15, ty = t >> 4;
  int f0 = bf * 64, r0 = br * 64;
  float acc[4][4] = {};
  for (int g0 = f0; g0 < F; g0 += 32) {
    {
      int rr = t >> 2, kq = t & 3;
      const float* zr = &Z[(r0 + rr) * F + g0 + kq * 8];
      float4 a0 = *(const float4*)zr;
      float4 a1 = *(const float4*)(zr + 4);
      As[kq * 8 + 0][rr] = a0.x; As[kq * 8 + 1][rr] = a0.y;
      As[kq * 8 + 2][rr] = a0.z; As[kq * 8 + 3][rr] = a0.w;
      As[kq * 8 + 4][rr] = a1.x; As[kq * 8 + 5][rr] = a1.y;
      As[kq * 8 + 6][rr] = a1.z; As[kq * 8 + 7][rr] = a1.w;
      int col = t & 63, kr = t >> 6;
#pragma unroll
      for (int kk = 0; kk < 32; kk += 4)
        Bs[kr + kk][col] = LI[(g0 + kr + kk) * F + f0 + col];
    }
    __syncthreads();
#pragma unroll
    for (int k = 0; k < 32; ++k) {
      float4 a4 = *(const float4*)&As[k][ty * 4];
      float4 b4 = *(const float4*)&Bs[k][tx * 4];
      float av[4] = {a4.x, a4.y, a4.z, a4.w};
      float bv[4] = {b4.x, b4.y, b4.z, b4.w};
#pragma unroll
      for (int r = 0; r < 4; ++r)
#pragma unroll
        for (int c = 0; c < 4; ++c) acc[r][c] += av[r] * bv[c];
    }
    __syncthreads();
  }
#pragma unroll
  for (int r = 0; r < 4; ++r) {
    int row = r0 + ty * 4 + r;
    int o = row & 255;
    float4 mv = *(const float4*)&meanT[o * F + f0 + tx * 4];
    float4 st = make_float4(acc[r][0] + mv.x, acc[r][1] + mv.y,
                            acc[r][2] + mv.z, acc[r][3] + mv.w);
    *(float4*)&out[row * F + f0 + tx * 4] = st;
  }
}

// ---------------- logpq: per-(s,slice) f64 partial sums ----------------
__global__ __launch_bounds__(256) void k_logpq_part(const float* __restrict__ C,
                                                    const float* __restrict__ Zp,
                                                    double* __restrict__ parts) {
  int s = blockIdx.y, slice = blockIdx.x;
  const int per = (OUTC * F) / 8;   // 18432
  int base = s * OUTC * F + slice * per;
  double ssq = 0.0, zsq = 0.0;
  for (int idx = threadIdx.x * 4; idx < per; idx += 1024) {
    float4 c = *(const float4*)&C[base + idx];
    float4 z = *(const float4*)&Zp[base + idx];
    ssq += (double)c.x * c.x + (double)c.y * c.y + (double)c.z * c.z + (double)c.w * c.w;
    zsq += (double)z.x * z.x + (double)z.y * z.y + (double)z.z * z.z + (double)z.w * z.w;
  }
  __shared__ double sA[256], sB[256];
  sA[threadIdx.x] = ssq; sB[threadIdx.x] = zsq;
  __syncthreads();
  for (int o = 128; o > 0; o >>= 1) {
    if (threadIdx.x < o) { sA[threadIdx.x] += sA[threadIdx.x + o]; sB[threadIdx.x] += sB[threadIdx.x + o]; }
    __syncthreads();
  }
  if (threadIdx.x == 0) {
    parts[(s * 8 + slice) * 2 + 0] = sA[0];
    parts[(s * 8 + slice) * 2 + 1] = sB[0];
  }
}

// ---------------- logpq final: logdet from LI diag (L[t][t] = 1/LI[t][t] exactly) ----------------
__global__ __launch_bounds__(576) void k_logpq_final(const float* __restrict__ LI,
                                                     const double* __restrict__ parts,
                                                     float* __restrict__ out) {
  __shared__ double red[576];
  int t = threadIdx.x;
  red[t] = log((double)LI[t * F + t]);   // = -log(L[t][t])
  __syncthreads();
  for (int o = 512; o > 0; o >>= 1) {
    if (t < o && t + o < 576) red[t] += red[t + o];
    __syncthreads();
  }
  double ldsumLI = red[0];               // = -sum_f log(L_ff)
  if (t < SNUM) {
    double ssq = 0.0, zsq = 0.0;
    for (int k = 0; k < 8; ++k) {
      ssq += parts[(t * 8 + k) * 2 + 0];
      zsq += parts[(t * 8 + k) * 2 + 1];
    }
    double pp = 576.0;
    double lpq = -0.5 * pp * ssq
               + 0.5 * (double)(OUTC * F) * log(pp)
               + 0.5 * zsq
               + (double)OUTC * ldsumLI;
    out[SNUM * OUTC * F + t] = (float)lpq;
  }
}

// ---------------- launch ----------------
extern "C" void kernel_launch(void* const* d_in, const int* in_sizes, int n_in,
                              void* d_out, int out_size, void* d_ws, size_t ws_size,
                              hipStream_t stream) {
  (void)in_sizes; (void)n_in; (void)out_size; (void)ws_size;
  const float* X  = (const float*)d_in[1];   // Xi_param [1,576,576]
  const float* u  = (const float*)d_in[2];   // u [256,576,1]
  const float* lp = (const float*)d_in[3];   // log_prec_scaled [1,1,576]
  const float* Z  = (const float*)d_in[4];   // Z [64,256,576,1]
  float* out = (float*)d_out;

  float* ws    = (float*)d_ws;
  float* G     = ws;                 // 576*576
  float* LI    = G + F * F;          // 576*576 (Linv, natural orientation)
  float* Yb    = LI + F * F;         // 576*256
  float* Tb    = Yb + F * OUTC;      // 576*256  (aliased as trigemm temp Tw)
  float* meanT = Tb + F * OUTC;      // 256*576
  double* parts = (double*)(meanT + F * OUTC);  // 64*8*2 doubles
  float* Tw = Tb;

  k_gemm_G<<<dim3(9, 9), 256, 0, stream>>>(X, lp, G);
  k_gemm_Y<<<dim3(4, 9), 256, 0, stream>>>(X, u, lp, Yb);

  // ---- blocked Cholesky, NB = 64 ----
  for (int k = 0; k < 9; ++k) {
    int k0 = k * 64;
    k_chol_diag64<<<1, 64, 0, stream>>>(G, k0);
    int n = F - k0 - 64;
    if (n > 0) {
      k_chol_panel64<<<n / 16, 256, 0, stream>>>(G, k0);
      k_chol_upd64<<<dim3(n / 64, n / 64), 256, 0, stream>>>(G, k0);
    }
  }

  // ---- recursive blocked triangular inverse: LI = inv(L), 576 = 512 + 64 ----
  k_zero<<<(F * F) / 1024, 256, 0, stream>>>(LI);
  k_base_inv64<<<9, 256, 0, stream>>>(G, LI);
  // level 1: 4 pairs n=64 (within 0..512)
  k_trigemm<<<dim3(1, 1, 4), 256, 0, stream>>>(G + 64 * F, F, 128 * (F + 1),
                                               LI, F, 128 * (F + 1),
                                               Tw, 64, 64 * 64, 64, 64, 64, 1.0f);
  k_trigemm<<<dim3(1, 1, 4), 256, 0, stream>>>(LI + 64 * (F + 1), F, 128 * (F + 1),
                                               Tw, 64, 64 * 64,
                                               LI + 64 * F, F, 128 * (F + 1), 64, 64, 64, -1.0f);
  // level 2: 2 pairs n=128 (offsets 0, 256)
  k_trigemm<<<dim3(2, 2, 2), 256, 0, stream>>>(G + 128 * F, F, 256 * (F + 1),
                                               LI, F, 256 * (F + 1),
                                               Tw, 128, 128 * 128, 128, 128, 128, 1.0f);
  k_trigemm<<<dim3(2, 2, 2), 256, 0, stream>>>(LI + 128 * (F + 1), F, 256 * (F + 1),
                                               Tw, 128, 128 * 128,
                                               LI + 128 * F, F, 256 * (F + 1), 128, 128, 128, -1.0f);
  // level 3: 1 pair n=256
  k_trigemm<<<dim3(4, 4, 1), 256, 0, stream>>>(G + 256 * F, F, 0,
                                               LI, F, 0,
                                               Tw, 256, 0, 256, 256, 256, 1.0f);
  k_trigemm<<<dim3(4, 4, 1), 256, 0, stream>>>(LI + 256 * (F + 1), F, 0,
                                               Tw, 256, 0,
                                               LI + 256 * F, F, 0, 256, 256, 256, -1.0f);
  // level 4: 512 + 64   (T = B @ Ainv is 64x512 with K=512; LI21 = -Cinv @ T has K=64!)
  k_trigemm<<<dim3(8, 1, 1), 256, 0, stream>>>(G + 512 * F, F, 0,
                                               LI, F, 0,
                                               Tw, 512, 0, 64, 512, 512, 1.0f);
  k_trigemm<<<dim3(8, 1, 1), 256, 0, stream>>>(LI + 512 * (F + 1), F, 0,
                                               Tw, 512, 0,
                                               LI + 512 * F, F, 0, 64, 512, 64, -1.0f);

  k_gemm_T<<<dim3(4, 9), 256, 0, stream>>>(LI, Yb, Tb);
  k_gemm_mean<<<dim3(9, 4), 256, 0, stream>>>(LI, Tb, meanT);
  k_big<<<dim3(9, 256), 256, 0, stream>>>(Z, LI, meanT, out);
  k_logpq_part<<<dim3(8, 64), 256, 0, stream>>>(out, Z, parts);
  k_logpq_final<<<1, 576, 0, stream>>>(LI, parts, out);
}

// Round 6
// 756.903 us; speedup vs baseline: 2.2883x; 1.1823x over previous
//
#include <hip/hip_runtime.h>

#define F 576
#define OUTC 256
#define SNUM 64
#define PP 576.0f
#define NBLK 36

// ---------------- device-scope spin barrier (all NBLK blocks resident) ----------------
__device__ __forceinline__ void gbar(int* cnt, int* gen) {
  __syncthreads();
  if (threadIdx.x == 0) {
    int g = __hip_atomic_load(gen, __ATOMIC_ACQUIRE, __HIP_MEMORY_SCOPE_AGENT);
    int old = __hip_atomic_fetch_add(cnt, 1, __ATOMIC_ACQ_REL, __HIP_MEMORY_SCOPE_AGENT);
    if (old == NBLK - 1) {
      __hip_atomic_store(cnt, 0, __ATOMIC_RELAXED, __HIP_MEMORY_SCOPE_AGENT);
      __hip_atomic_fetch_add(gen, 1, __ATOMIC_ACQ_REL, __HIP_MEMORY_SCOPE_AGENT);
    } else {
      while (__hip_atomic_load(gen, __ATOMIC_ACQUIRE, __HIP_MEMORY_SCOPE_AGENT) == g) {
        __builtin_amdgcn_s_sleep(1);
      }
    }
  }
  __syncthreads();
}

// ---------------- shared inner product 64x64 += As^T-ish (proven round-5 core) ----------------
__device__ __forceinline__ void mm16(const float (*As)[68], const float (*Bs)[68],
                                     float acc[4][4], int tx, int ty) {
#pragma unroll
  for (int k = 0; k < 32; ++k) {
    float4 a4 = *(const float4*)&As[k][ty * 4];
    float4 b4 = *(const float4*)&Bs[k][tx * 4];
    float av[4] = {a4.x, a4.y, a4.z, a4.w};
    float bv[4] = {b4.x, b4.y, b4.z, b4.w};
#pragma unroll
    for (int r = 0; r < 4; ++r)
#pragma unroll
      for (int c = 0; c < 4; ++c) acc[r][c] += av[r] * bv[c];
  }
}

// ---------------- generic 64x64 tile of C = sgn * A@B (A row-major f4 stage, B k-major) ----------------
__device__ void tile_gemm(const float* __restrict__ A, int lda,
                          const float* __restrict__ B, int ldb,
                          float* __restrict__ C, int ldc,
                          int m0, int n0, int K, float sgn,
                          float (*As)[68], float (*Bs)[68]) {
  int t = threadIdx.x, tx = t & 15, ty = t >> 4;
  float acc[4][4] = {};
  for (int k0 = 0; k0 < K; k0 += 32) {
    int rr = t >> 2, kq = t & 3;
    const float* ap = &A[(m0 + rr) * lda + k0 + kq * 8];
    float4 a0 = *(const float4*)ap;
    float4 a1 = *(const float4*)(ap + 4);
    As[kq*8+0][rr] = a0.x; As[kq*8+1][rr] = a0.y;
    As[kq*8+2][rr] = a0.z; As[kq*8+3][rr] = a0.w;
    As[kq*8+4][rr] = a1.x; As[kq*8+5][rr] = a1.y;
    As[kq*8+6][rr] = a1.z; As[kq*8+7][rr] = a1.w;
    int col = t & 63, kr = t >> 6;
#pragma unroll
    for (int kk = 0; kk < 32; kk += 4)
      Bs[kr + kk][col] = B[(k0 + kr + kk) * ldb + n0 + col];
    __syncthreads();
    mm16(As, Bs, acc, tx, ty);
    __syncthreads();
  }
#pragma unroll
  for (int r = 0; r < 4; ++r)
#pragma unroll
    for (int c = 0; c < 4; ++c)
      C[(m0 + ty*4 + r) * ldc + n0 + tx*4 + c] = sgn * acc[r][c];
}

// ---------------- serial 64x64 Cholesky on LDS tile (wave 0), proven shfl version ----------------
__device__ void diag_factor(float* Ts /* 64x66 */) {
  int t = threadIdx.x;
  __syncthreads();
  if (t < 64) {
    int l = t;
    float r[64];
#pragma unroll
    for (int g = 0; g < 64; ++g) r[g] = Ts[l*66 + g];
#pragma unroll
    for (int j = 0; j < 64; ++j) {
      float d = __shfl(r[j], j, 64);
      float inv = 1.0f / sqrtf(d);
      float c = r[j] * inv;
      r[j] = c;
#pragma unroll
      for (int g = j + 1; g < 64; ++g)
        r[g] = fmaf(-__shfl(c, g, 64), c, r[g]);
    }
#pragma unroll
    for (int g = 0; g < 64; ++g) Ts[l*66 + g] = r[g];
  }
  __syncthreads();
}

// ---------------- panel solve: 16 rows per block (4 waves x 4 rows), proven ----------------
__device__ void panel_phase(float* __restrict__ G, int k0, int b,
                            float* Ts, float* invd) {
  int t = threadIdx.x;
  for (int idx = t; idx < 64 * 64; idx += 256) {
    int i = idx >> 6, j = idx & 63;
    Ts[i*66 + j] = G[(k0 + i) * F + k0 + j];
  }
  __syncthreads();
  if (t < 64) invd[t] = 1.0f / Ts[t*66 + t];
  __syncthreads();
  int l = t & 63, w = t >> 6;
  int r0 = k0 + 64 + b * 16 + w * 4;
  float v0 = G[(r0 + 0) * F + k0 + l];
  float v1 = G[(r0 + 1) * F + k0 + l];
  float v2 = G[(r0 + 2) * F + k0 + l];
  float v3 = G[(r0 + 3) * F + k0 + l];
#pragma unroll
  for (int j = 0; j < 64; ++j) {
    float dj = invd[j];
    float x0 = __shfl(v0, j, 64) * dj;
    float x1 = __shfl(v1, j, 64) * dj;
    float x2 = __shfl(v2, j, 64) * dj;
    float x3 = __shfl(v3, j, 64) * dj;
    if (l > j) {
      float lj = Ts[l*66 + j];
      v0 = fmaf(-x0, lj, v0);
      v1 = fmaf(-x1, lj, v1);
      v2 = fmaf(-x2, lj, v2);
      v3 = fmaf(-x3, lj, v3);
    }
  }
  float dl = invd[l];
  G[(r0 + 0) * F + k0 + l] = v0 * dl;
  G[(r0 + 1) * F + k0 + l] = v1 * dl;
  G[(r0 + 2) * F + k0 + l] = v2 * dl;
  G[(r0 + 3) * F + k0 + l] = v3 * dl;
}

// ---------------- rank-64 trailing update tile (+ fused next-diag for tile (0,0)) ----------------
__device__ void upd_phase(float* __restrict__ G, int k0, int ti, int tj, bool fuse,
                          float (*As)[68], float (*Bs)[68], float* Ts) {
  int b0 = k0 + 64;
  int i0 = b0 + ti * 64, j0 = b0 + tj * 64;
  int t = threadIdx.x, tx = t & 15, ty = t >> 4;
  float acc[4][4] = {};
  for (int kk0 = 0; kk0 < 64; kk0 += 32) {
    for (int idx = t; idx < 64 * 32; idx += 256) {
      int ii = idx >> 5, kk = idx & 31;
      As[kk][ii] = G[(i0 + ii) * F + k0 + kk0 + kk];
      Bs[kk][ii] = G[(j0 + ii) * F + k0 + kk0 + kk];
    }
    __syncthreads();
#pragma unroll
    for (int k = 0; k < 32; ++k) {
      float a[4], b[4];
#pragma unroll
      for (int m = 0; m < 4; ++m) { a[m] = As[k][ty*4 + m]; b[m] = Bs[k][tx*4 + m]; }
#pragma unroll
      for (int r = 0; r < 4; ++r)
#pragma unroll
        for (int c = 0; c < 4; ++c) acc[r][c] += a[r] * b[c];
    }
    __syncthreads();
  }
  if (!fuse) {
#pragma unroll
    for (int r = 0; r < 4; ++r)
#pragma unroll
      for (int c = 0; c < 4; ++c)
        G[(i0 + ty*4 + r) * F + j0 + tx*4 + c] -= acc[r][c];
  } else {
    // build updated tile in LDS, factor it, write lower triangle only
#pragma unroll
    for (int r = 0; r < 4; ++r)
#pragma unroll
      for (int c = 0; c < 4; ++c)
        Ts[(ty*4 + r)*66 + tx*4 + c] =
            G[(i0 + ty*4 + r) * F + j0 + tx*4 + c] - acc[r][c];
    diag_factor(Ts);
    for (int idx = t; idx < 64 * 64; idx += 256) {
      int i = idx >> 6, j = idx & 63;
      if (j <= i) G[(i0 + i) * F + j0 + j] = Ts[i*66 + j];
    }
  }
}

// ---------------- invert diagonal 64x64 triangular block -> LI (proven shfl version) ----------------
__device__ void base_inv_phase(const float* __restrict__ G, float* __restrict__ LI,
                               int blk, float* Ts, float* invd) {
  int base = blk * 64, t = threadIdx.x;
  for (int idx = t; idx < 64 * 64; idx += 256) {
    int i = idx >> 6, j = idx & 63;
    Ts[i*66 + j] = G[(base + i) * F + base + j];
  }
  __syncthreads();
  if (t < 64) invd[t] = 1.0f / Ts[t*66 + t];
  __syncthreads();
  int l = t & 63, w = t >> 6;
  float v[16];
#pragma unroll
  for (int c = 0; c < 16; ++c) v[c] = (l == (w * 16 + c)) ? 1.0f : 0.0f;
#pragma unroll
  for (int j = 0; j < 64; ++j) {
    float dj = invd[j];
    float lj = (l > j) ? Ts[l*66 + j] : 0.0f;
#pragma unroll
    for (int c = 0; c < 16; ++c) {
      float x = __shfl(v[c], j, 64) * dj;
      v[c] = fmaf(-x, lj, v[c]);
    }
  }
  float dl = invd[l];
#pragma unroll
  for (int c = 0; c < 16; ++c)
    LI[(base + l) * F + base + w * 16 + c] = v[c] * dl;
}

// ---------------- meanT[o][f] = sum_g LI[g][f] T[g][o]  (proven round-5 body) ----------------
__device__ void mean_phase(const float* __restrict__ LI, const float* __restrict__ T,
                           float* __restrict__ meanT, int bf, int bo,
                           float (*As)[68], float (*Bs)[68]) {
  int t = threadIdx.x, tx = t & 15, ty = t >> 4;
  int f0 = bf * 64, o0 = bo * 64;
  float acc[4][4] = {};
  for (int g0 = f0; g0 < F; g0 += 32) {
    int col = t & 63, kr = t >> 6;
#pragma unroll
    for (int kk = 0; kk < 32; kk += 4) {
      As[kr + kk][col] = T[(g0 + kr + kk) * OUTC + o0 + col];
      Bs[kr + kk][col] = LI[(g0 + kr + kk) * F + f0 + col];
    }
    __syncthreads();
    mm16(As, Bs, acc, tx, ty);
    __syncthreads();
  }
#pragma unroll
  for (int r = 0; r < 4; ++r) {
    float4 st = make_float4(acc[r][0], acc[r][1], acc[r][2], acc[r][3]);
    *(float4*)&meanT[(o0 + ty*4 + r) * F + f0 + tx*4] = st;
  }
}

// ================= k_mid: Cholesky + inversion + gemm_T + gemm_mean, one launch =================
__global__ __launch_bounds__(256) void k_mid(float* __restrict__ G, float* __restrict__ LI,
                                             const float* __restrict__ Yb,
                                             float* __restrict__ Tb, float* __restrict__ meanT,
                                             int* __restrict__ ctl) {
  __shared__ float As[32][68];
  __shared__ float Bs[32][68];
  __shared__ float Ts[64 * 66];
  __shared__ float invd[64];
  int* cnt = ctl;
  int* gen = ctl + 1;
  int b = blockIdx.x, t = threadIdx.x;
  float* Tw = Tb;   // trigemm temp; consumed before Tb written by gemm_T phase

  // ---- diag k=0 ----
  if (b == 0) {
    for (int idx = t; idx < 64 * 64; idx += 256) {
      int i = idx >> 6, j = idx & 63;
      Ts[i*66 + j] = G[i * F + j];
    }
    diag_factor(Ts);
    for (int idx = t; idx < 64 * 64; idx += 256) {
      int i = idx >> 6, j = idx & 63;
      if (j <= i) G[i * F + j] = Ts[i*66 + j];
    }
  }
  gbar(cnt, gen);

  // ---- blocked right-looking Cholesky, diag(k+1) fused into upd(k) ----
  for (int k = 0; k < 8; ++k) {
    int k0 = k * 64;
    int n = 512 - k0;            // rows below current diag
    if (b < n / 16) panel_phase(G, k0, b, Ts, invd);
    gbar(cnt, gen);
    int nt = n / 64, ntiles = nt * (nt + 1) / 2;
    if (b < ntiles) {
      int ti = 0, bb = b;
      while (bb >= ti + 1) { bb -= ti + 1; ++ti; }
      int tj = bb;
      upd_phase(G, k0, ti, tj, (ti == 0 && tj == 0), As, Bs, Ts);
    }
    gbar(cnt, gen);
  }

  // ---- base inversions + zero off-diagonal LI blocks ----
  if (b < 9) {
    base_inv_phase(G, LI, b, Ts, invd);
  } else {
    int m = b - 9;
    for (int q = m; q < 72; q += 27) {
      int r = q / 8, cc = q % 8;
      int c = cc + (cc >= r ? 1 : 0);
      for (int idx = t; idx < 64 * 16; idx += 256) {
        int i = idx >> 4, jj = idx & 15;
        ((float4*)&LI[(r * 64 + i) * F + c * 64])[jj] = make_float4(0.f, 0.f, 0.f, 0.f);
      }
    }
  }
  gbar(cnt, gen);

  // ---- recursive triangular inverse levels (576 = 512 + 64) ----
  // L1: 4 pairs n=64
  if (b < 4) tile_gemm(G + 64*F + b*128*(F+1), F, LI + b*128*(F+1), F,
                       Tw + b*4096, 64, 0, 0, 64, 1.0f, As, Bs);
  gbar(cnt, gen);
  if (b < 4) tile_gemm(LI + 64*(F+1) + b*128*(F+1), F, Tw + b*4096, 64,
                       LI + 64*F + b*128*(F+1), F, 0, 0, 64, -1.0f, As, Bs);
  gbar(cnt, gen);
  // L2: 2 pairs n=128
  if (b < 8) {
    int z = b >> 2, tl = b & 3;
    tile_gemm(G + 128*F + z*256*(F+1), F, LI + z*256*(F+1), F,
              Tw + z*16384, 128, (tl>>1)*64, (tl&1)*64, 128, 1.0f, As, Bs);
  }
  gbar(cnt, gen);
  if (b < 8) {
    int z = b >> 2, tl = b & 3;
    tile_gemm(LI + 128*(F+1) + z*256*(F+1), F, Tw + z*16384, 128,
              LI + 128*F + z*256*(F+1), F, (tl>>1)*64, (tl&1)*64, 128, -1.0f, As, Bs);
  }
  gbar(cnt, gen);
  // L3: 1 pair n=256
  if (b < 16) tile_gemm(G + 256*F, F, LI, F, Tw, 256,
                        (b>>2)*64, (b&3)*64, 256, 1.0f, As, Bs);
  gbar(cnt, gen);
  if (b < 16) tile_gemm(LI + 256*(F+1), F, Tw, 256, LI + 256*F, F,
                        (b>>2)*64, (b&3)*64, 256, -1.0f, As, Bs);
  gbar(cnt, gen);
  // L4: 512 + 64  (T: M=64,N=512,K=512 ; E: K=64)
  if (b < 8) tile_gemm(G + 512*F, F, LI, F, Tw, 512, 0, b*64, 512, 1.0f, As, Bs);
  gbar(cnt, gen);
  if (b < 8) tile_gemm(LI + 512*(F+1), F, Tw, 512, LI + 512*F, F, 0, b*64, 64, -1.0f, As, Bs);
  gbar(cnt, gen);

  // ---- gemm_T: Tb[g][o] = sum_h LI[g][h] Yb[h][o]  (K = g0+64, triangular) ----
  {
    int bg = b >> 2, bo = b & 3;
    tile_gemm(LI, F, Yb, OUTC, Tb, OUTC, bg * 64, bo * 64, bg * 64 + 64, 1.0f, As, Bs);
  }
  gbar(cnt, gen);

  // ---- gemm_mean ----
  {
    int bf = b >> 2, bo = b & 3;
    mean_phase(LI, Tb, meanT, bf, bo, As, Bs);
  }
}

// ================= k_gy: G and Y builds merged (z-split) =================
__global__ __launch_bounds__(256) void k_gy(const float* __restrict__ X,
                                            const float* __restrict__ u,
                                            const float* __restrict__ lp,
                                            float* __restrict__ G,
                                            float* __restrict__ Y) {
  __shared__ float As[32][68];
  __shared__ float Bs[32][68];
  int t = threadIdx.x, tx = t & 15, ty = t >> 4;
  if (blockIdx.z == 0) {
    int bi = blockIdx.y, bj = blockIdx.x;
    if (bj > bi) return;
    int f0 = bi * 64, g0 = bj * 64;
    float acc[4][4] = {};
    for (int i0 = 0; i0 < F; i0 += 32) {
      int col = t & 63, kr = t >> 6;
#pragma unroll
      for (int kk = 0; kk < 32; kk += 4) {
        int i = i0 + kr + kk;
        float e = expf(lp[i]);
        As[kr + kk][col] = e * X[i * F + f0 + col];
        Bs[kr + kk][col] = X[i * F + g0 + col];
      }
      __syncthreads();
      mm16(As, Bs, acc, tx, ty);
      __syncthreads();
    }
#pragma unroll
    for (int r = 0; r < 4; ++r) {
      int gr = f0 + ty*4 + r;
#pragma unroll
      for (int c = 0; c < 4; ++c) {
        int gc = g0 + tx*4 + c;
        float v = acc[r][c];
        if (gr == gc) v += PP;
        G[gr * F + gc] = v;
      }
    }
  } else {
    if (blockIdx.x >= 4) return;
    int bo = blockIdx.x, bf = blockIdx.y;
    int f0 = bf * 64, o0 = bo * 64;
    float acc[4][4] = {};
    for (int i0 = 0; i0 < F; i0 += 32) {
      {
        int col = t & 63, kr = t >> 6;
#pragma unroll
        for (int kk = 0; kk < 32; kk += 4) {
          int i = i0 + kr + kk;
          As[kr + kk][col] = expf(lp[i]) * X[i * F + f0 + col];
        }
        int oo = t >> 2, kq = t & 3;
        const float* ur = &u[(o0 + oo) * F + i0 + kq * 8];
        float4 u0 = *(const float4*)ur;
        float4 u1 = *(const float4*)(ur + 4);
        Bs[kq*8+0][oo] = u0.x; Bs[kq*8+1][oo] = u0.y;
        Bs[kq*8+2][oo] = u0.z; Bs[kq*8+3][oo] = u0.w;
        Bs[kq*8+4][oo] = u1.x; Bs[kq*8+5][oo] = u1.y;
        Bs[kq*8+6][oo] = u1.z; Bs[kq*8+7][oo] = u1.w;
      }
      __syncthreads();
      mm16(As, Bs, acc, tx, ty);
      __syncthreads();
    }
#pragma unroll
    for (int r = 0; r < 4; ++r) {
      float4 st = make_float4(acc[r][0], acc[r][1], acc[r][2], acc[r][3]);
      *(float4*)&Y[(f0 + ty*4 + r) * OUTC + o0 + tx*4] = st;
    }
  }
}

// ================= k_big: out = Z@Linv + mean, fused f64 logpq partials =================
__global__ __launch_bounds__(256) void k_big(const float* __restrict__ Z,
                                             const float* __restrict__ LI,
                                             const float* __restrict__ meanT,
                                             float* __restrict__ out,
                                             double* __restrict__ parts) {
  int bf = blockIdx.x, br = blockIdx.y;
  __shared__ float As[32][68];
  __shared__ float Bs[32][68];
  __shared__ double redA[256];
  __shared__ double redB[256];
  int t = threadIdx.x, tx = t & 15, ty = t >> 4;
  int f0 = bf * 64, r0 = br * 64;
  float acc[4][4] = {};
  double zsq = 0.0;
  for (int g0 = f0; g0 < F; g0 += 32) {
    {
      int rr = t >> 2, kq = t & 3;
      const float* zr = &Z[(r0 + rr) * F + g0 + kq * 8];
      float4 a0 = *(const float4*)zr;
      float4 a1 = *(const float4*)(zr + 4);
      if (bf == 0) {
        zsq += (double)a0.x*a0.x + (double)a0.y*a0.y + (double)a0.z*a0.z + (double)a0.w*a0.w
             + (double)a1.x*a1.x + (double)a1.y*a1.y + (double)a1.z*a1.z + (double)a1.w*a1.w;
      }
      As[kq*8+0][rr] = a0.x; As[kq*8+1][rr] = a0.y;
      As[kq*8+2][rr] = a0.z; As[kq*8+3][rr] = a0.w;
      As[kq*8+4][rr] = a1.x; As[kq*8+5][rr] = a1.y;
      As[kq*8+6][rr] = a1.z; As[kq*8+7][rr] = a1.w;
      int col = t & 63, kr = t >> 6;
#pragma unroll
      for (int kk = 0; kk < 32; kk += 4)
        Bs[kr + kk][col] = LI[(g0 + kr + kk) * F + f0 + col];
    }
    __syncthreads();
    mm16(As, Bs, acc, tx, ty);
    __syncthreads();
  }
  double ssq = 0.0;
#pragma unroll
  for (int r = 0; r < 4; ++r) {
    int row = r0 + ty*4 + r;
    int o = row & 255;
    float4 mv = *(const float4*)&meanT[o * F + f0 + tx*4];
    float4 st = make_float4(acc[r][0] + mv.x, acc[r][1] + mv.y,
                            acc[r][2] + mv.z, acc[r][3] + mv.w);
    *(float4*)&out[row * F + f0 + tx*4] = st;
    ssq += (double)st.x*st.x + (double)st.y*st.y + (double)st.z*st.z + (double)st.w*st.w;
  }
  redA[t] = ssq; redB[t] = zsq;
  __syncthreads();
  for (int o = 128; o > 0; o >>= 1) {
    if (t < o) { redA[t] += redA[t + o]; redB[t] += redB[t + o]; }
    __syncthreads();
  }
  if (t == 0) {
    int s = br >> 2;
    atomicAdd(&parts[s * 2 + 0], redA[0]);
    if (bf == 0) atomicAdd(&parts[s * 2 + 1], redB[0]);
  }
}

// ================= logpq final =================
__global__ __launch_bounds__(576) void k_logpq_final(const float* __restrict__ LI,
                                                     const double* __restrict__ parts,
                                                     float* __restrict__ out) {
  __shared__ double red[576];
  int t = threadIdx.x;
  red[t] = log((double)LI[t * F + t]);   // = -log(L[t][t])
  __syncthreads();
  for (int o = 512; o > 0; o >>= 1) {
    if (t < o && t + o < 576) red[t] += red[t + o];
    __syncthreads();
  }
  double ldsumLI = red[0];
  if (t < SNUM) {
    double ssq = parts[t * 2 + 0];
    double zsq = parts[t * 2 + 1];
    double pp = 576.0;
    double lpq = -0.5 * pp * ssq
               + 0.5 * (double)(OUTC * F) * log(pp)
               + 0.5 * zsq
               + (double)OUTC * ldsumLI;
    out[SNUM * OUTC * F + t] = (float)lpq;
  }
}

// ================= launch =================
extern "C" void kernel_launch(void* const* d_in, const int* in_sizes, int n_in,
                              void* d_out, int out_size, void* d_ws, size_t ws_size,
                              hipStream_t stream) {
  (void)in_sizes; (void)n_in; (void)out_size; (void)ws_size;
  const float* X  = (const float*)d_in[1];   // Xi_param [1,576,576]
  const float* u  = (const float*)d_in[2];   // u [256,576,1]
  const float* lp = (const float*)d_in[3];   // log_prec_scaled [1,1,576]
  const float* Z  = (const float*)d_in[4];   // Z [64,256,576,1]
  float* out = (float*)d_out;

  float* ws    = (float*)d_ws;
  float* G     = ws;                   // 331776
  float* LI    = ws + 331776;          // 331776
  float* Yb    = ws + 663552;          // 147456
  float* Tb    = ws + 811008;          // 147456 (also trigemm temp)
  float* meanT = ws + 958464;          // 147456
  double* parts = (double*)(ws + 1105920);        // 128 doubles (1024 B)
  int*    ctl   = (int*)(ws + 1105920 + 256);     // 2 ints

  hipMemsetAsync((void*)(ws + 1105920), 0, 1032, stream);
  k_gy<<<dim3(9, 9, 2), 256, 0, stream>>>(X, u, lp, G, Yb);
  k_mid<<<NBLK, 256, 0, stream>>>(G, LI, Yb, Tb, meanT, ctl);
  k_big<<<dim3(9, 256), 256, 0, stream>>>(Z, LI, meanT, out, parts);
  k_logpq_final<<<1, 576, 0, stream>>>(LI, parts, out);
}

// Round 7
// 699.626 us; speedup vs baseline: 2.4756x; 1.0819x over previous
//
#include <hip/hip_runtime.h>

#define F 576
#define OUTC 256
#define SNUM 64
#define PP 576.0f
#define NBLK 36

// ---------------- device-scope barrier: one wb/inv per block per barrier ----------------
// arrival: release-fence (wbL2) + relaxed add; spin: relaxed ATOMIC load (coherent,
// no bulk invalidate per poll); exit: acquire-fence (inv). Monotonic counter.
__device__ __forceinline__ void gbar(int* cnt, int barid) {
  __syncthreads();
  if (threadIdx.x == 0) {
    __builtin_amdgcn_fence(__ATOMIC_RELEASE, "agent");
    __hip_atomic_fetch_add(cnt, 1, __ATOMIC_RELAXED, __HIP_MEMORY_SCOPE_AGENT);
    int target = barid * NBLK;
    while (__hip_atomic_load(cnt, __ATOMIC_RELAXED, __HIP_MEMORY_SCOPE_AGENT) < target) {
      __builtin_amdgcn_s_sleep(2);
    }
    __builtin_amdgcn_fence(__ATOMIC_ACQUIRE, "agent");
  }
  __syncthreads();
}

// ---------------- shared inner product (proven core) ----------------
__device__ __forceinline__ void mm16(const float (*As)[68], const float (*Bs)[68],
                                     float acc[4][4], int tx, int ty) {
#pragma unroll
  for (int k = 0; k < 32; ++k) {
    float4 a4 = *(const float4*)&As[k][ty * 4];
    float4 b4 = *(const float4*)&Bs[k][tx * 4];
    float av[4] = {a4.x, a4.y, a4.z, a4.w};
    float bv[4] = {b4.x, b4.y, b4.z, b4.w};
#pragma unroll
    for (int r = 0; r < 4; ++r)
#pragma unroll
      for (int c = 0; c < 4; ++c) acc[r][c] += av[r] * bv[c];
  }
}

// ---------------- generic 64x64 tile of C = sgn * A@B ----------------
__device__ void tile_gemm(const float* __restrict__ A, int lda,
                          const float* __restrict__ B, int ldb,
                          float* __restrict__ C, int ldc,
                          int m0, int n0, int K, float sgn,
                          float (*As)[68], float (*Bs)[68]) {
  int t = threadIdx.x, tx = t & 15, ty = t >> 4;
  float acc[4][4] = {};
  for (int k0 = 0; k0 < K; k0 += 32) {
    int rr = t >> 2, kq = t & 3;
    const float* ap = &A[(m0 + rr) * lda + k0 + kq * 8];
    float4 a0 = *(const float4*)ap;
    float4 a1 = *(const float4*)(ap + 4);
    As[kq*8+0][rr] = a0.x; As[kq*8+1][rr] = a0.y;
    As[kq*8+2][rr] = a0.z; As[kq*8+3][rr] = a0.w;
    As[kq*8+4][rr] = a1.x; As[kq*8+5][rr] = a1.y;
    As[kq*8+6][rr] = a1.z; As[kq*8+7][rr] = a1.w;
    int col = t & 63, kr = t >> 6;
#pragma unroll
    for (int kk = 0; kk < 32; kk += 4)
      Bs[kr + kk][col] = B[(k0 + kr + kk) * ldb + n0 + col];
    __syncthreads();
    mm16(As, Bs, acc, tx, ty);
    __syncthreads();
  }
#pragma unroll
  for (int r = 0; r < 4; ++r)
#pragma unroll
    for (int c = 0; c < 4; ++c)
      C[(m0 + ty*4 + r) * ldc + n0 + tx*4 + c] = sgn * acc[r][c];
}

// ---------------- serial 64x64 Cholesky on LDS tile (wave 0) ----------------
__device__ void diag_factor(float* Ts /* 64x66 */) {
  int t = threadIdx.x;
  __syncthreads();
  if (t < 64) {
    int l = t;
    float r[64];
#pragma unroll
    for (int g = 0; g < 64; ++g) r[g] = Ts[l*66 + g];
#pragma unroll
    for (int j = 0; j < 64; ++j) {
      float d = __shfl(r[j], j, 64);
      float inv = 1.0f / sqrtf(d);
      float c = r[j] * inv;
      r[j] = c;
#pragma unroll
      for (int g = j + 1; g < 64; ++g)
        r[g] = fmaf(-__shfl(c, g, 64), c, r[g]);
    }
#pragma unroll
    for (int g = 0; g < 64; ++g) Ts[l*66 + g] = r[g];
  }
  __syncthreads();
}

// ---------------- panel solve: 16 rows per block (4 waves x 4 rows) ----------------
__device__ void panel_phase(float* __restrict__ G, int k0, int b,
                            float* Ts, float* invd) {
  int t = threadIdx.x;
  for (int idx = t; idx < 64 * 64; idx += 256) {
    int i = idx >> 6, j = idx & 63;
    Ts[i*66 + j] = G[(k0 + i) * F + k0 + j];
  }
  __syncthreads();
  if (t < 64) invd[t] = 1.0f / Ts[t*66 + t];
  __syncthreads();
  int l = t & 63, w = t >> 6;
  int r0 = k0 + 64 + b * 16 + w * 4;
  float v0 = G[(r0 + 0) * F + k0 + l];
  float v1 = G[(r0 + 1) * F + k0 + l];
  float v2 = G[(r0 + 2) * F + k0 + l];
  float v3 = G[(r0 + 3) * F + k0 + l];
#pragma unroll
  for (int j = 0; j < 64; ++j) {
    float dj = invd[j];
    float x0 = __shfl(v0, j, 64) * dj;
    float x1 = __shfl(v1, j, 64) * dj;
    float x2 = __shfl(v2, j, 64) * dj;
    float x3 = __shfl(v3, j, 64) * dj;
    if (l > j) {
      float lj = Ts[l*66 + j];
      v0 = fmaf(-x0, lj, v0);
      v1 = fmaf(-x1, lj, v1);
      v2 = fmaf(-x2, lj, v2);
      v3 = fmaf(-x3, lj, v3);
    }
  }
  float dl = invd[l];
  G[(r0 + 0) * F + k0 + l] = v0 * dl;
  G[(r0 + 1) * F + k0 + l] = v1 * dl;
  G[(r0 + 2) * F + k0 + l] = v2 * dl;
  G[(r0 + 3) * F + k0 + l] = v3 * dl;
}

// ---------------- rank-64 trailing update tile (+ fused next-diag for tile (0,0)) ----------------
__device__ void upd_phase(float* __restrict__ G, int k0, int ti, int tj, bool fuse,
                          float (*As)[68], float (*Bs)[68], float* Ts) {
  int b0 = k0 + 64;
  int i0 = b0 + ti * 64, j0 = b0 + tj * 64;
  int t = threadIdx.x, tx = t & 15, ty = t >> 4;
  float acc[4][4] = {};
  for (int kk0 = 0; kk0 < 64; kk0 += 32) {
    for (int idx = t; idx < 64 * 32; idx += 256) {
      int ii = idx >> 5, kk = idx & 31;
      As[kk][ii] = G[(i0 + ii) * F + k0 + kk0 + kk];
      Bs[kk][ii] = G[(j0 + ii) * F + k0 + kk0 + kk];
    }
    __syncthreads();
#pragma unroll
    for (int k = 0; k < 32; ++k) {
      float a[4], b[4];
#pragma unroll
      for (int m = 0; m < 4; ++m) { a[m] = As[k][ty*4 + m]; b[m] = Bs[k][tx*4 + m]; }
#pragma unroll
      for (int r = 0; r < 4; ++r)
#pragma unroll
        for (int c = 0; c < 4; ++c) acc[r][c] += a[r] * b[c];
    }
    __syncthreads();
  }
  if (!fuse) {
#pragma unroll
    for (int r = 0; r < 4; ++r)
#pragma unroll
      for (int c = 0; c < 4; ++c)
        G[(i0 + ty*4 + r) * F + j0 + tx*4 + c] -= acc[r][c];
  } else {
#pragma unroll
    for (int r = 0; r < 4; ++r)
#pragma unroll
      for (int c = 0; c < 4; ++c)
        Ts[(ty*4 + r)*66 + tx*4 + c] =
            G[(i0 + ty*4 + r) * F + j0 + tx*4 + c] - acc[r][c];
    diag_factor(Ts);
    for (int idx = t; idx < 64 * 64; idx += 256) {
      int i = idx >> 6, j = idx & 63;
      if (j <= i) G[(i0 + i) * F + j0 + j] = Ts[i*66 + j];
    }
  }
}

// ---------------- invert diagonal 64x64 triangular block -> LI ----------------
__device__ void base_inv_phase(const float* __restrict__ G, float* __restrict__ LI,
                               int blk, float* Ts, float* invd) {
  int base = blk * 64, t = threadIdx.x;
  for (int idx = t; idx < 64 * 64; idx += 256) {
    int i = idx >> 6, j = idx & 63;
    Ts[i*66 + j] = G[(base + i) * F + base + j];
  }
  __syncthreads();
  if (t < 64) invd[t] = 1.0f / Ts[t*66 + t];
  __syncthreads();
  int l = t & 63, w = t >> 6;
  float v[16];
#pragma unroll
  for (int c = 0; c < 16; ++c) v[c] = (l == (w * 16 + c)) ? 1.0f : 0.0f;
#pragma unroll
  for (int j = 0; j < 64; ++j) {
    float dj = invd[j];
    float lj = (l > j) ? Ts[l*66 + j] : 0.0f;
#pragma unroll
    for (int c = 0; c < 16; ++c) {
      float x = __shfl(v[c], j, 64) * dj;
      v[c] = fmaf(-x, lj, v[c]);
    }
  }
  float dl = invd[l];
#pragma unroll
  for (int c = 0; c < 16; ++c)
    LI[(base + l) * F + base + w * 16 + c] = v[c] * dl;
}

// ---------------- meanT[o][f] = sum_g LI[g][f] T[g][o] ----------------
__device__ void mean_phase(const float* __restrict__ LI, const float* __restrict__ T,
                           float* __restrict__ meanT, int bf, int bo,
                           float (*As)[68], float (*Bs)[68]) {
  int t = threadIdx.x, tx = t & 15, ty = t >> 4;
  int f0 = bf * 64, o0 = bo * 64;
  float acc[4][4] = {};
  for (int g0 = f0; g0 < F; g0 += 32) {
    int col = t & 63, kr = t >> 6;
#pragma unroll
    for (int kk = 0; kk < 32; kk += 4) {
      As[kr + kk][col] = T[(g0 + kr + kk) * OUTC + o0 + col];
      Bs[kr + kk][col] = LI[(g0 + kr + kk) * F + f0 + col];
    }
    __syncthreads();
    mm16(As, Bs, acc, tx, ty);
    __syncthreads();
  }
#pragma unroll
  for (int r = 0; r < 4; ++r) {
    float4 st = make_float4(acc[r][0], acc[r][1], acc[r][2], acc[r][3]);
    *(float4*)&meanT[(o0 + ty*4 + r) * F + f0 + tx*4] = st;
  }
}

// ================= k_mid: Cholesky + inversion + gemm_T + gemm_mean, one launch =================
__global__ __launch_bounds__(256) void k_mid(float* __restrict__ G, float* __restrict__ LI,
                                             const float* __restrict__ Yb,
                                             float* __restrict__ Tb, float* __restrict__ meanT,
                                             int* __restrict__ ctl) {
  __shared__ float As[32][68];
  __shared__ float Bs[32][68];
  __shared__ float Ts[64 * 66];
  __shared__ float invd[64];
  int* cnt = ctl;
  int bar = 0;
  int b = blockIdx.x, t = threadIdx.x;
  float* Tw = Tb;   // trigemm temp; consumed before Tb written by gemm_T phase

  // ---- diag k=0 ----
  if (b == 0) {
    for (int idx = t; idx < 64 * 64; idx += 256) {
      int i = idx >> 6, j = idx & 63;
      Ts[i*66 + j] = G[i * F + j];
    }
    diag_factor(Ts);
    for (int idx = t; idx < 64 * 64; idx += 256) {
      int i = idx >> 6, j = idx & 63;
      if (j <= i) G[i * F + j] = Ts[i*66 + j];
    }
  }
  gbar(cnt, ++bar);

  // ---- blocked right-looking Cholesky, diag(k+1) fused into upd(k) ----
  for (int k = 0; k < 8; ++k) {
    int k0 = k * 64;
    int n = 512 - k0;            // rows below current diag
    if (b < n / 16) panel_phase(G, k0, b, Ts, invd);
    gbar(cnt, ++bar);
    int nt = n / 64, ntiles = nt * (nt + 1) / 2;
    if (b < ntiles) {
      int ti = 0, bb = b;
      while (bb >= ti + 1) { bb -= ti + 1; ++ti; }
      int tj = bb;
      upd_phase(G, k0, ti, tj, (ti == 0 && tj == 0), As, Bs, Ts);
    }
    gbar(cnt, ++bar);
  }

  // ---- base inversions + zero off-diagonal LI blocks ----
  if (b < 9) {
    base_inv_phase(G, LI, b, Ts, invd);
  } else {
    int m = b - 9;
    for (int q = m; q < 72; q += 27) {
      int r = q / 8, cc = q % 8;
      int c = cc + (cc >= r ? 1 : 0);
      for (int idx = t; idx < 64 * 16; idx += 256) {
        int i = idx >> 4, jj = idx & 15;
        ((float4*)&LI[(r * 64 + i) * F + c * 64])[jj] = make_float4(0.f, 0.f, 0.f, 0.f);
      }
    }
  }
  gbar(cnt, ++bar);

  // ---- recursive triangular inverse levels (576 = 512 + 64) ----
  // L1: 4 pairs n=64
  if (b < 4) tile_gemm(G + 64*F + b*128*(F+1), F, LI + b*128*(F+1), F,
                       Tw + b*4096, 64, 0, 0, 64, 1.0f, As, Bs);
  gbar(cnt, ++bar);
  if (b < 4) tile_gemm(LI + 64*(F+1) + b*128*(F+1), F, Tw + b*4096, 64,
                       LI + 64*F + b*128*(F+1), F, 0, 0, 64, -1.0f, As, Bs);
  gbar(cnt, ++bar);
  // L2: 2 pairs n=128
  if (b < 8) {
    int z = b >> 2, tl = b & 3;
    tile_gemm(G + 128*F + z*256*(F+1), F, LI + z*256*(F+1), F,
              Tw + z*16384, 128, (tl>>1)*64, (tl&1)*64, 128, 1.0f, As, Bs);
  }
  gbar(cnt, ++bar);
  if (b < 8) {
    int z = b >> 2, tl = b & 3;
    tile_gemm(LI + 128*(F+1) + z*256*(F+1), F, Tw + z*16384, 128,
              LI + 128*F + z*256*(F+1), F, (tl>>1)*64, (tl&1)*64, 128, -1.0f, As, Bs);
  }
  gbar(cnt, ++bar);
  // L3: 1 pair n=256
  if (b < 16) tile_gemm(G + 256*F, F, LI, F, Tw, 256,
                        (b>>2)*64, (b&3)*64, 256, 1.0f, As, Bs);
  gbar(cnt, ++bar);
  if (b < 16) tile_gemm(LI + 256*(F+1), F, Tw, 256, LI + 256*F, F,
                        (b>>2)*64, (b&3)*64, 256, -1.0f, As, Bs);
  gbar(cnt, ++bar);
  // L4: 512 + 64  (T: M=64,N=512,K=512 ; E: K=64)
  if (b < 8) tile_gemm(G + 512*F, F, LI, F, Tw, 512, 0, b*64, 512, 1.0f, As, Bs);
  gbar(cnt, ++bar);
  if (b < 8) tile_gemm(LI + 512*(F+1), F, Tw, 512, LI + 512*F, F, 0, b*64, 64, -1.0f, As, Bs);
  gbar(cnt, ++bar);

  // ---- gemm_T: Tb[g][o] = sum_h LI[g][h] Yb[h][o]  (K = g0+64, triangular) ----
  {
    int bg = b >> 2, bo = b & 3;
    tile_gemm(LI, F, Yb, OUTC, Tb, OUTC, bg * 64, bo * 64, bg * 64 + 64, 1.0f, As, Bs);
  }
  gbar(cnt, ++bar);

  // ---- gemm_mean ----
  {
    int bf = b >> 2, bo = b & 3;
    mean_phase(LI, Tb, meanT, bf, bo, As, Bs);
  }
}

// ================= k_gy: G and Y builds merged (z-split) =================
__global__ __launch_bounds__(256) void k_gy(const float* __restrict__ X,
                                            const float* __restrict__ u,
                                            const float* __restrict__ lp,
                                            float* __restrict__ G,
                                            float* __restrict__ Y) {
  __shared__ float As[32][68];
  __shared__ float Bs[32][68];
  int t = threadIdx.x, tx = t & 15, ty = t >> 4;
  if (blockIdx.z == 0) {
    int bi = blockIdx.y, bj = blockIdx.x;
    if (bj > bi) return;
    int f0 = bi * 64, g0 = bj * 64;
    float acc[4][4] = {};
    for (int i0 = 0; i0 < F; i0 += 32) {
      int col = t & 63, kr = t >> 6;
#pragma unroll
      for (int kk = 0; kk < 32; kk += 4) {
        int i = i0 + kr + kk;
        float e = expf(lp[i]);
        As[kr + kk][col] = e * X[i * F + f0 + col];
        Bs[kr + kk][col] = X[i * F + g0 + col];
      }
      __syncthreads();
      mm16(As, Bs, acc, tx, ty);
      __syncthreads();
    }
#pragma unroll
    for (int r = 0; r < 4; ++r) {
      int gr = f0 + ty*4 + r;
#pragma unroll
      for (int c = 0; c < 4; ++c) {
        int gc = g0 + tx*4 + c;
        float v = acc[r][c];
        if (gr == gc) v += PP;
        G[gr * F + gc] = v;
      }
    }
  } else {
    if (blockIdx.x >= 4) return;
    int bo = blockIdx.x, bf = blockIdx.y;
    int f0 = bf * 64, o0 = bo * 64;
    float acc[4][4] = {};
    for (int i0 = 0; i0 < F; i0 += 32) {
      {
        int col = t & 63, kr = t >> 6;
#pragma unroll
        for (int kk = 0; kk < 32; kk += 4) {
          int i = i0 + kr + kk;
          As[kr + kk][col] = expf(lp[i]) * X[i * F + f0 + col];
        }
        int oo = t >> 2, kq = t & 3;
        const float* ur = &u[(o0 + oo) * F + i0 + kq * 8];
        float4 u0 = *(const float4*)ur;
        float4 u1 = *(const float4*)(ur + 4);
        Bs[kq*8+0][oo] = u0.x; Bs[kq*8+1][oo] = u0.y;
        Bs[kq*8+2][oo] = u0.z; Bs[kq*8+3][oo] = u0.w;
        Bs[kq*8+4][oo] = u1.x; Bs[kq*8+5][oo] = u1.y;
        Bs[kq*8+6][oo] = u1.z; Bs[kq*8+7][oo] = u1.w;
      }
      __syncthreads();
      mm16(As, Bs, acc, tx, ty);
      __syncthreads();
    }
#pragma unroll
    for (int r = 0; r < 4; ++r) {
      float4 st = make_float4(acc[r][0], acc[r][1], acc[r][2], acc[r][3]);
      *(float4*)&Y[(f0 + ty*4 + r) * OUTC + o0 + tx*4] = st;
    }
  }
}

// ================= k_big: out = Z@Linv + mean, fused f64 logpq partials =================
__global__ __launch_bounds__(256) void k_big(const float* __restrict__ Z,
                                             const float* __restrict__ LI,
                                             const float* __restrict__ meanT,
                                             float* __restrict__ out,
                                             double* __restrict__ parts) {
  int bf = blockIdx.x, br = blockIdx.y;
  __shared__ float As[32][68];
  __shared__ float Bs[32][68];
  __shared__ double redA[256];
  __shared__ double redB[256];
  int t = threadIdx.x, tx = t & 15, ty = t >> 4;
  int f0 = bf * 64, r0 = br * 64;
  float acc[4][4] = {};
  double zsq = 0.0;
  for (int g0 = f0; g0 < F; g0 += 32) {
    {
      int rr = t >> 2, kq = t & 3;
      const float* zr = &Z[(r0 + rr) * F + g0 + kq * 8];
      float4 a0 = *(const float4*)zr;
      float4 a1 = *(const float4*)(zr + 4);
      if (bf == 0) {
        zsq += (double)a0.x*a0.x + (double)a0.y*a0.y + (double)a0.z*a0.z + (double)a0.w*a0.w
             + (double)a1.x*a1.x + (double)a1.y*a1.y + (double)a1.z*a1.z + (double)a1.w*a1.w;
      }
      As[kq*8+0][rr] = a0.x; As[kq*8+1][rr] = a0.y;
      As[kq*8+2][rr] = a0.z; As[kq*8+3][rr] = a0.w;
      As[kq*8+4][rr] = a1.x; As[kq*8+5][rr] = a1.y;
      As[kq*8+6][rr] = a1.z; As[kq*8+7][rr] = a1.w;
      int col = t & 63, kr = t >> 6;
#pragma unroll
      for (int kk = 0; kk < 32; kk += 4)
        Bs[kr + kk][col] = LI[(g0 + kr + kk) * F + f0 + col];
    }
    __syncthreads();
    mm16(As, Bs, acc, tx, ty);
    __syncthreads();
  }
  double ssq = 0.0;
#pragma unroll
  for (int r = 0; r < 4; ++r) {
    int row = r0 + ty*4 + r;
    int o = row & 255;
    float4 mv = *(const float4*)&meanT[o * F + f0 + tx*4];
    float4 st = make_float4(acc[r][0] + mv.x, acc[r][1] + mv.y,
                            acc[r][2] + mv.z, acc[r][3] + mv.w);
    *(float4*)&out[row * F + f0 + tx*4] = st;
    ssq += (double)st.x*st.x + (double)st.y*st.y + (double)st.z*st.z + (double)st.w*st.w;
  }
  redA[t] = ssq; redB[t] = zsq;
  __syncthreads();
  for (int o = 128; o > 0; o >>= 1) {
    if (t < o) { redA[t] += redA[t + o]; redB[t] += redB[t + o]; }
    __syncthreads();
  }
  if (t == 0) {
    int s = br >> 2;
    atomicAdd(&parts[s * 2 + 0], redA[0]);
    if (bf == 0) atomicAdd(&parts[s * 2 + 1], redB[0]);
  }
}

// ================= logpq final =================
__global__ __launch_bounds__(576) void k_logpq_final(const float* __restrict__ LI,
                                                     const double* __restrict__ parts,
                                                     float* __restrict__ out) {
  __shared__ double red[576];
  int t = threadIdx.x;
  red[t] = log((double)LI[t * F + t]);   // = -log(L[t][t])
  __syncthreads();
  for (int o = 512; o > 0; o >>= 1) {
    if (t < o && t + o < 576) red[t] += red[t + o];
    __syncthreads();
  }
  double ldsumLI = red[0];
  if (t < SNUM) {
    double ssq = parts[t * 2 + 0];
    double zsq = parts[t * 2 + 1];
    double pp = 576.0;
    double lpq = -0.5 * pp * ssq
               + 0.5 * (double)(OUTC * F) * log(pp)
               + 0.5 * zsq
               + (double)OUTC * ldsumLI;
    out[SNUM * OUTC * F + t] = (float)lpq;
  }
}

// ================= launch =================
extern "C" void kernel_launch(void* const* d_in, const int* in_sizes, int n_in,
                              void* d_out, int out_size, void* d_ws, size_t ws_size,
                              hipStream_t stream) {
  (void)in_sizes; (void)n_in; (void)out_size; (void)ws_size;
  const float* X  = (const float*)d_in[1];   // Xi_param [1,576,576]
  const float* u  = (const float*)d_in[2];   // u [256,576,1]
  const float* lp = (const float*)d_in[3];   // log_prec_scaled [1,1,576]
  const float* Z  = (const float*)d_in[4];   // Z [64,256,576,1]
  float* out = (float*)d_out;

  float* ws    = (float*)d_ws;
  float* G     = ws;                   // 331776
  float* LI    = ws + 331776;          // 331776
  float* Yb    = ws + 663552;          // 147456
  float* Tb    = ws + 811008;          // 147456 (also trigemm temp)
  float* meanT = ws + 958464;          // 147456
  double* parts = (double*)(ws + 1105920);        // 128 doubles (1024 B)
  int*    ctl   = (int*)(ws + 1105920 + 256);     // 2 ints

  hipMemsetAsync((void*)(ws + 1105920), 0, 1032, stream);
  k_gy<<<dim3(9, 9, 2), 256, 0, stream>>>(X, u, lp, G, Yb);
  k_mid<<<NBLK, 256, 0, stream>>>(G, LI, Yb, Tb, meanT, ctl);
  k_big<<<dim3(9, 256), 256, 0, stream>>>(Z, LI, meanT, out, parts);
  k_logpq_final<<<1, 576, 0, stream>>>(LI, parts, out);
}